// Round 1
// baseline (22259.363 us; speedup 1.0000x reference)
//
#include <hip/hip_runtime.h>
#include <hip/hip_bf16.h>
#include <math.h>

#define B_     8
#define IMG_   224
#define PATCH_ 16
#define CIN_   3
#define D_     768
#define NH_    12
#define DEPTH_ 12
#define NE_    8
#define NCLS_  1000
#define DH_    3072
#define HD_    64
#define GRD_   14
#define NPAT_  196
#define NTOK_  197
#define T_     (B_*NTOK_)    /* 1576 tokens */
#define TP_    (B_*NPAT_)    /* 1568 patches */
#define NSLOT_ (T_*2)        /* 3152 (token,slot) pairs */
#define NCHUNK_ 15

static __device__ __forceinline__ float gelu_f(float x){
    return 0.5f * x * (1.0f + erff(x * 0.70710678118654752440f));
}

// ---------------- patch gather: x[B,3,224,224] -> pbuf[1568,768] (c,i,j) ----
__global__ void k_patch_gather(const float* __restrict__ x, float* __restrict__ pbuf){
    int idx = blockIdx.x*256 + threadIdx.x;
    if (idx >= TP_*D_) return;
    int k  = idx % D_;
    int tp = idx / D_;
    int p  = tp % NPAT_, b = tp / NPAT_;
    int c  = k >> 8;
    int ij = k & 255;
    int i  = ij >> 4, j = ij & 15;
    int gi = p / GRD_, gj = p % GRD_;
    pbuf[idx] = x[(((size_t)b*CIN_ + c)*IMG_ + gi*PATCH_ + i)*IMG_ + gj*PATCH_ + j];
}

// ---------------- generic GEMM: C[M,N] = act(A[M,K] @ W[N,K]^T + bias) (+res)
// 128x128 tile, BK=16, 256 threads, 8x8 per thread.
template<int ACT, int RES, int GATHER>
__global__ __launch_bounds__(256) void k_gemm(
    const float* __restrict__ A, const int* __restrict__ gidx,
    const float* __restrict__ W, const float* __restrict__ bias,
    const float* __restrict__ res, float* __restrict__ C,
    int M, int N, int K)
{
    __shared__ float As[128][17];
    __shared__ float Ws[128][17];
    const int tid = threadIdx.x;
    const int bm = blockIdx.y*128, bn = blockIdx.x*128;
    const int lr = tid >> 1;            // 0..127
    const int lc = (tid & 1) * 8;       // 0 or 8
    const int ty = tid >> 4, tx = tid & 15;
    float acc[8][8] = {};
    for (int k0 = 0; k0 < K; k0 += 16) {
        float4 a0 = make_float4(0,0,0,0), a1 = make_float4(0,0,0,0);
        int ar = bm + lr;
        if (ar < M) {
            int arow = GATHER ? (gidx[ar] >> 1) : ar;
            const float* ap = A + (size_t)arow*K + k0 + lc;
            a0 = *reinterpret_cast<const float4*>(ap);
            a1 = *reinterpret_cast<const float4*>(ap + 4);
        }
        const float* wp = W + (size_t)(bn + lr)*K + k0 + lc;
        float4 w0 = *reinterpret_cast<const float4*>(wp);
        float4 w1 = *reinterpret_cast<const float4*>(wp + 4);
        As[lr][lc+0]=a0.x; As[lr][lc+1]=a0.y; As[lr][lc+2]=a0.z; As[lr][lc+3]=a0.w;
        As[lr][lc+4]=a1.x; As[lr][lc+5]=a1.y; As[lr][lc+6]=a1.z; As[lr][lc+7]=a1.w;
        Ws[lr][lc+0]=w0.x; Ws[lr][lc+1]=w0.y; Ws[lr][lc+2]=w0.z; Ws[lr][lc+3]=w0.w;
        Ws[lr][lc+4]=w1.x; Ws[lr][lc+5]=w1.y; Ws[lr][lc+6]=w1.z; Ws[lr][lc+7]=w1.w;
        __syncthreads();
        #pragma unroll
        for (int kk = 0; kk < 16; ++kk) {
            float a[8], b[8];
            #pragma unroll
            for (int i=0;i<8;i++) a[i] = As[ty*8+i][kk];
            #pragma unroll
            for (int j=0;j<8;j++) b[j] = Ws[tx*8+j][kk];
            #pragma unroll
            for (int i=0;i<8;i++)
                #pragma unroll
                for (int j=0;j<8;j++)
                    acc[i][j] = fmaf(a[i], b[j], acc[i][j]);
        }
        __syncthreads();
    }
    #pragma unroll
    for (int i=0;i<8;i++){
        int m = bm + ty*8 + i;
        if (m >= M) continue;
        #pragma unroll
        for (int j=0;j<8;j++){
            int n = bn + tx*8 + j;
            float v = acc[i][j] + bias[n];
            if (ACT == 1) v = gelu_f(v);
            if (RES) v += res[(size_t)m*N + n];
            C[(size_t)m*N + n] = v;
        }
    }
}

// ---------------- MoE GEMM over gathered rows of one expert ------------------
template<int ACT, int GATHER>
__global__ __launch_bounds__(256) void k_gemm_moe(
    const float* __restrict__ A, const int* __restrict__ gidx,
    const float* __restrict__ Wl, const float* __restrict__ bl,
    float* __restrict__ C, const int* __restrict__ off, const int* __restrict__ cnt,
    int N, int K)
{
    __shared__ float As[128][17];
    __shared__ float Ws[128][17];
    const int e = blockIdx.z;
    const int o = off[e], c = cnt[e];
    const int row0 = o + blockIdx.y*128;
    if (row0 >= o + c) return;
    const int rend = o + c;
    const float* W    = Wl + (size_t)e*N*K;
    const float* bias = bl + (size_t)e*N;
    const int tid = threadIdx.x;
    const int bn = blockIdx.x*128;
    const int lr = tid >> 1;
    const int lc = (tid & 1) * 8;
    const int ty = tid >> 4, tx = tid & 15;
    float acc[8][8] = {};
    for (int k0 = 0; k0 < K; k0 += 16) {
        float4 a0 = make_float4(0,0,0,0), a1 = make_float4(0,0,0,0);
        int g = row0 + lr;
        if (g < rend) {
            int arow = GATHER ? (gidx[g] >> 1) : g;
            const float* ap = A + (size_t)arow*K + k0 + lc;
            a0 = *reinterpret_cast<const float4*>(ap);
            a1 = *reinterpret_cast<const float4*>(ap + 4);
        }
        const float* wp = W + (size_t)(bn + lr)*K + k0 + lc;
        float4 w0 = *reinterpret_cast<const float4*>(wp);
        float4 w1 = *reinterpret_cast<const float4*>(wp + 4);
        As[lr][lc+0]=a0.x; As[lr][lc+1]=a0.y; As[lr][lc+2]=a0.z; As[lr][lc+3]=a0.w;
        As[lr][lc+4]=a1.x; As[lr][lc+5]=a1.y; As[lr][lc+6]=a1.z; As[lr][lc+7]=a1.w;
        Ws[lr][lc+0]=w0.x; Ws[lr][lc+1]=w0.y; Ws[lr][lc+2]=w0.z; Ws[lr][lc+3]=w0.w;
        Ws[lr][lc+4]=w1.x; Ws[lr][lc+5]=w1.y; Ws[lr][lc+6]=w1.z; Ws[lr][lc+7]=w1.w;
        __syncthreads();
        #pragma unroll
        for (int kk = 0; kk < 16; ++kk) {
            float a[8], b[8];
            #pragma unroll
            for (int i=0;i<8;i++) a[i] = As[ty*8+i][kk];
            #pragma unroll
            for (int j=0;j<8;j++) b[j] = Ws[tx*8+j][kk];
            #pragma unroll
            for (int i=0;i<8;i++)
                #pragma unroll
                for (int j=0;j<8;j++)
                    acc[i][j] = fmaf(a[i], b[j], acc[i][j]);
        }
        __syncthreads();
    }
    #pragma unroll
    for (int i=0;i<8;i++){
        int g = row0 + ty*8 + i;
        if (g >= rend) continue;
        #pragma unroll
        for (int j=0;j<8;j++){
            int n = bn + tx*8 + j;
            float v = acc[i][j] + bias[n];
            if (ACT == 1) v = gelu_f(v);
            C[(size_t)g*N + n] = v;
        }
    }
}

// ---------------- LayerNorm (two-pass, block per row) ------------------------
__global__ __launch_bounds__(256) void k_ln(const float* __restrict__ X,
        const float* __restrict__ w, const float* __restrict__ b,
        float* __restrict__ Y, int in_mul)
{
    const int r = blockIdx.x;
    const float* xr = X + (size_t)r*in_mul*D_;
    float* yr = Y + (size_t)r*D_;
    const int tid = threadIdx.x;
    float v0 = xr[tid], v1 = xr[tid+256], v2 = xr[tid+512];
    __shared__ float red[8];
    const int wid = tid >> 6, lane = tid & 63;
    float s = v0 + v1 + v2;
    for (int m=32;m>0;m>>=1) s += __shfl_xor(s, m);
    if (lane == 0) red[wid] = s;
    __syncthreads();
    if (tid == 0) red[4] = (red[0]+red[1]+red[2]+red[3]) * (1.0f/768.0f);
    __syncthreads();
    const float mean = red[4];
    float d0 = v0-mean, d1 = v1-mean, d2 = v2-mean;
    float q = d0*d0 + d1*d1 + d2*d2;
    for (int m=32;m>0;m>>=1) q += __shfl_xor(q, m);
    if (lane == 0) red[wid] = q;
    __syncthreads();
    if (tid == 0) {
        float var = (red[0]+red[1]+red[2]+red[3]) * (1.0f/768.0f);
        red[5] = 1.0f / sqrtf(var + 1e-5f);
    }
    __syncthreads();
    const float rstd = red[5];
    yr[tid    ] = d0*rstd*w[tid    ] + b[tid    ];
    yr[tid+256] = d1*rstd*w[tid+256] + b[tid+256];
    yr[tid+512] = d2*rstd*w[tid+512] + b[tid+512];
}

// ---------------- fused attention: block per (chunk, head, batch) ------------
__global__ __launch_bounds__(256) void k_attn(const float* __restrict__ qkv,
                                              float* __restrict__ out)
{
    const int chunk = blockIdx.x;
    const int h = blockIdx.y;
    const int b = blockIdx.z;
    const int tid = threadIdx.x;
    __shared__ float Ks[NTOK_][HD_+1];
    __shared__ float qs[HD_];
    __shared__ float ps[NTOK_];
    __shared__ float red[8];
    __shared__ float obuf[4][HD_];
    const size_t basek = (size_t)b*NTOK_*2304 + 768 + h*HD_;
    for (int idx = tid; idx < NTOK_*HD_; idx += 256){
        int m = idx >> 6, d = idx & 63;
        Ks[m][d] = qkv[basek + (size_t)m*2304 + d];
    }
    __syncthreads();
    const int n0 = chunk*14;
    const int n1 = min(n0+14, NTOK_);
    const int wid = tid >> 6, lane = tid & 63;
    for (int n = n0; n < n1; ++n){
        const size_t baseq = (size_t)(b*NTOK_+n)*2304 + h*HD_;
        if (tid < HD_) qs[tid] = qkv[baseq + tid];
        __syncthreads();
        float sc = -3.0e38f;
        if (tid < NTOK_){
            float dot = 0.0f;
            #pragma unroll 8
            for (int d=0; d<HD_; ++d) dot = fmaf(qs[d], Ks[tid][d], dot);
            sc = dot * 0.125f;
        }
        float mv = sc;
        for (int m=32;m>0;m>>=1) mv = fmaxf(mv, __shfl_xor(mv, m));
        if (lane == 0) red[wid] = mv;
        __syncthreads();
        if (tid == 0) red[4] = fmaxf(fmaxf(red[0],red[1]), fmaxf(red[2],red[3]));
        __syncthreads();
        const float mx = red[4];
        float ev = (tid < NTOK_) ? expf(sc - mx) : 0.0f;
        if (tid < NTOK_) ps[tid] = ev;
        float sv = ev;
        for (int m=32;m>0;m>>=1) sv += __shfl_xor(sv, m);
        if (lane == 0) red[wid] = sv;
        __syncthreads();
        if (tid == 0) red[5] = red[0]+red[1]+red[2]+red[3];
        __syncthreads();
        const float inv = 1.0f / red[5];
        // output phase: (d, quarter) decomposition
        const int d = tid & 63, q4 = tid >> 6;
        float acc = 0.0f;
        const size_t basev = (size_t)b*NTOK_*2304 + 1536 + h*HD_ + d;
        for (int m = q4; m < NTOK_; m += 4)
            acc = fmaf(ps[m], qkv[basev + (size_t)m*2304], acc);
        obuf[q4][d] = acc;
        __syncthreads();
        if (tid < HD_){
            float ov = (obuf[0][tid]+obuf[1][tid]+obuf[2][tid]+obuf[3][tid]) * inv;
            out[(size_t)(b*NTOK_+n)*D_ + h*HD_ + tid] = ov;
        }
        __syncthreads();
    }
}

// ---------------- MoE gate: wave per token -----------------------------------
__global__ __launch_bounds__(256) void k_gate(const float* __restrict__ X,
        const float* __restrict__ gw, const float* __restrict__ gb,
        int* __restrict__ t_e, float* __restrict__ t_sc, int* __restrict__ counts)
{
    const int wid = threadIdx.x >> 6, lane = threadIdx.x & 63;
    const int tok = blockIdx.x*4 + wid;
    if (tok >= T_) return;
    float acc[NE_] = {};
    for (int k = lane; k < D_; k += 64){
        float xv = X[(size_t)tok*D_ + k];
        #pragma unroll
        for (int e=0;e<NE_;e++) acc[e] = fmaf(xv, gw[e*D_+k], acc[e]);
    }
    #pragma unroll
    for (int e=0;e<NE_;e++)
        for (int m=32;m>0;m>>=1) acc[e] += __shfl_xor(acc[e], m);
    if (lane == 0){
        float l[NE_];
        #pragma unroll
        for (int e=0;e<NE_;e++) l[e] = acc[e] + gb[e];
        int i0 = 0;
        for (int e=1;e<NE_;e++) if (l[e] > l[i0]) i0 = e;
        int i1 = -1;
        for (int e=0;e<NE_;e++) if (e != i0 && (i1 < 0 || l[e] > l[i1])) i1 = e;
        float e1 = expf(l[i1] - l[i0]);
        float s = 1.0f + e1;
        t_e[tok*2]   = i0;  t_e[tok*2+1]  = i1;
        t_sc[tok*2]  = 1.0f/s; t_sc[tok*2+1] = e1/s;
        atomicAdd(&counts[i0], 1);
        atomicAdd(&counts[i1], 1);
    }
}

__global__ void k_scan(const int* __restrict__ counts, int* __restrict__ off,
                       int* __restrict__ cnt2){
    if (threadIdx.x == 0){
        int s = 0;
        for (int e=0;e<NE_;e++){ off[e] = s; s += counts[e]; cnt2[e] = 0; }
    }
}

__global__ void k_scatter(const int* __restrict__ t_e, const int* __restrict__ off,
                          int* __restrict__ cnt2, int* __restrict__ gidx,
                          int* __restrict__ rg){
    int id = blockIdx.x*256 + threadIdx.x;
    if (id >= NSLOT_) return;
    int e = t_e[id];
    int pos = atomicAdd(&cnt2[e], 1);
    int g = off[e] + pos;
    gidx[g] = id;
    rg[id] = g;
}

__global__ void k_combine(const float* __restrict__ yb, const int* __restrict__ rg,
                          const float* __restrict__ t_sc, float* __restrict__ z){
    int idx = blockIdx.x*256 + threadIdx.x;
    if (idx >= T_*D_) return;
    int t = idx / D_, n = idx % D_;
    int g0 = rg[t*2], g1 = rg[t*2+1];
    z[idx] += t_sc[t*2]*yb[(size_t)g0*D_+n] + t_sc[t*2+1]*yb[(size_t)g1*D_+n];
}

// ---------------- z assembly: cls + pos / patchproj + pos --------------------
__global__ void k_assemble(const float* __restrict__ pe, const float* __restrict__ cls,
                           const float* __restrict__ pos, float* __restrict__ z){
    int idx = blockIdx.x*256 + threadIdx.x;
    if (idx >= T_*D_) return;
    int n = idx % D_, t = idx / D_;
    int b = t / NTOK_, r = t % NTOK_;
    float v;
    if (r == 0) v = cls[n] + pos[n];
    else        v = pe[((size_t)b*NPAT_ + (r-1))*D_ + n] + pos[(size_t)r*D_ + n];
    z[idx] = v;
}

// ---------------- head: block per batch, wave per 4 outputs ------------------
__global__ __launch_bounds__(256) void k_head(const float* __restrict__ zn,
        const float* __restrict__ hw, const float* __restrict__ hb,
        float* __restrict__ out)
{
    const int b = blockIdx.x;
    const int wid = threadIdx.x >> 6, lane = threadIdx.x & 63;
    for (int o = wid; o < NCLS_; o += 4){
        float acc = 0.0f;
        for (int k = lane; k < D_; k += 64)
            acc = fmaf(zn[b*D_+k], hw[(size_t)o*D_+k], acc);
        for (int m=32;m>0;m>>=1) acc += __shfl_xor(acc, m);
        if (lane == 0) out[b*NCLS_+o] = acc + hb[o];
    }
}

// =============================================================================
extern "C" void kernel_launch(void* const* d_in, const int* in_sizes, int n_in,
                              void* d_out, int out_size, void* d_ws, size_t ws_size,
                              hipStream_t stream)
{
    const float* x        = (const float*)d_in[0];
    const float* patch_w  = (const float*)d_in[1];
    const float* patch_b  = (const float*)d_in[2];
    const float* cls_tok  = (const float*)d_in[3];
    const float* pos_emb  = (const float*)d_in[4];
    const float* ln1_w    = (const float*)d_in[5];
    const float* ln1_b    = (const float*)d_in[6];
    const float* qkv_w    = (const float*)d_in[7];
    const float* qkv_b    = (const float*)d_in[8];
    const float* proj_w   = (const float*)d_in[9];
    const float* proj_b   = (const float*)d_in[10];
    const float* ln2_w    = (const float*)d_in[11];
    const float* ln2_b    = (const float*)d_in[12];
    const float* fc1_w    = (const float*)d_in[13];
    const float* fc1_b    = (const float*)d_in[14];
    const float* fc2_w    = (const float*)d_in[15];
    const float* fc2_b    = (const float*)d_in[16];
    const float* gate_w   = (const float*)d_in[17];
    const float* gate_b   = (const float*)d_in[18];
    const float* exp_w1   = (const float*)d_in[19];
    const float* exp_b1   = (const float*)d_in[20];
    const float* exp_w2   = (const float*)d_in[21];
    const float* exp_b2   = (const float*)d_in[22];
    const float* norm_w   = (const float*)d_in[23];
    const float* norm_b   = (const float*)d_in[24];
    const float* head_w   = (const float*)d_in[25];
    const float* head_b   = (const float*)d_in[26];

    char* wsb = (char*)d_ws;
    size_t off_ = 0;
    auto alloc = [&](size_t nelem, size_t esz) -> void* {
        void* p = wsb + off_;
        off_ += ((nelem*esz + 255) / 256) * 256;
        return p;
    };
    float* z      = (float*)alloc((size_t)T_*D_, 4);
    float* lnbuf  = (float*)alloc((size_t)T_*D_, 4);
    float* qkvbuf = (float*)alloc((size_t)T_*3*D_, 4);
    float* abuf   = (float*)alloc((size_t)T_*D_, 4);     // attn out / patch-proj out
    float* hid    = (float*)alloc((size_t)NSLOT_*DH_, 4); // MLP hidden (also pbuf)
    float* yb     = (float*)alloc((size_t)NSLOT_*D_, 4);
    float* t_sc   = (float*)alloc(NSLOT_, 4);
    float* zn     = (float*)alloc((size_t)B_*D_, 4);
    int*   t_e    = (int*)alloc(NSLOT_, 4);
    int*   rg     = (int*)alloc(NSLOT_, 4);
    int*   gidx   = (int*)alloc(NSLOT_, 4);
    int*   counts = (int*)alloc(8, 4);
    int*   offs   = (int*)alloc(8, 4);
    int*   cnt2   = (int*)alloc(8, 4);
    float* pbuf   = hid; // reuse: patch gather only needed before layer 0

    // ---- patch embedding ----
    k_patch_gather<<<dim3((TP_*D_+255)/256), 256, 0, stream>>>(x, pbuf);
    k_gemm<0,0,0><<<dim3(D_/128, (TP_+127)/128), 256, 0, stream>>>(
        pbuf, nullptr, patch_w, patch_b, nullptr, abuf, TP_, D_, D_);
    k_assemble<<<dim3((T_*D_+255)/256), 256, 0, stream>>>(abuf, cls_tok, pos_emb, z);

    int di = 0, mi = 0;
    for (int i = 0; i < DEPTH_; ++i){
        k_ln<<<T_, 256, 0, stream>>>(z, ln1_w + i*D_, ln1_b + i*D_, lnbuf, 1);
        k_gemm<0,0,0><<<dim3(3*D_/128, (T_+127)/128), 256, 0, stream>>>(
            lnbuf, nullptr, qkv_w + (size_t)i*3*D_*D_, qkv_b + (size_t)i*3*D_,
            nullptr, qkvbuf, T_, 3*D_, D_);
        k_attn<<<dim3(NCHUNK_, NH_, B_), 256, 0, stream>>>(qkvbuf, abuf);
        k_gemm<0,1,0><<<dim3(D_/128, (T_+127)/128), 256, 0, stream>>>(
            abuf, nullptr, proj_w + (size_t)i*D_*D_, proj_b + (size_t)i*D_,
            z, z, T_, D_, D_);
        k_ln<<<T_, 256, 0, stream>>>(z, ln2_w + i*D_, ln2_b + i*D_, lnbuf, 1);
        if (i & 1){ // MoE layers 1,3,5,7,9,11
            hipMemsetAsync(counts, 0, 8*sizeof(int), stream);
            k_gate<<<dim3((T_+3)/4), 256, 0, stream>>>(
                lnbuf, gate_w + (size_t)mi*NE_*D_, gate_b + (size_t)mi*NE_,
                t_e, t_sc, counts);
            k_scan<<<1, 64, 0, stream>>>(counts, offs, cnt2);
            k_scatter<<<dim3((NSLOT_+255)/256), 256, 0, stream>>>(t_e, offs, cnt2, gidx, rg);
            k_gemm_moe<1,1><<<dim3(DH_/128, (NSLOT_+127)/128, NE_), 256, 0, stream>>>(
                lnbuf, gidx, exp_w1 + (size_t)mi*NE_*DH_*D_, exp_b1 + (size_t)mi*NE_*DH_,
                hid, offs, counts, DH_, D_);
            k_gemm_moe<0,0><<<dim3(D_/128, (NSLOT_+127)/128, NE_), 256, 0, stream>>>(
                hid, nullptr, exp_w2 + (size_t)mi*NE_*D_*DH_, exp_b2 + (size_t)mi*NE_*D_,
                yb, offs, counts, D_, DH_);
            k_combine<<<dim3((T_*D_+255)/256), 256, 0, stream>>>(yb, rg, t_sc, z);
            mi++;
        } else {
            k_gemm<1,0,0><<<dim3(DH_/128, (T_+127)/128), 256, 0, stream>>>(
                lnbuf, nullptr, fc1_w + (size_t)di*DH_*D_, fc1_b + (size_t)di*DH_,
                nullptr, hid, T_, DH_, D_);
            k_gemm<0,1,0><<<dim3(D_/128, (T_+127)/128), 256, 0, stream>>>(
                hid, nullptr, fc2_w + (size_t)di*D_*DH_, fc2_b + (size_t)di*D_,
                z, z, T_, D_, DH_);
            di++;
        }
    }
    // ---- final LN on cls tokens only + head ----
    k_ln<<<B_, 256, 0, stream>>>(z, norm_w, norm_b, zn, NTOK_);
    k_head<<<B_, 256, 0, stream>>>(zn, head_w, head_b, (float*)d_out);
}

// Round 2
// 8178.551 us; speedup vs baseline: 2.7217x; 2.7217x over previous
//
#include <hip/hip_runtime.h>
#include <hip/hip_bf16.h>
#include <math.h>

#define B_     8
#define IMG_   224
#define PATCH_ 16
#define CIN_   3
#define D_     768
#define NH_    12
#define DEPTH_ 12
#define NE_    8
#define NCLS_  1000
#define DH_    3072
#define HD_    64
#define GRD_   14
#define NPAT_  196
#define NTOK_  197
#define T_     (B_*NTOK_)    /* 1576 tokens */
#define TP_    (B_*NPAT_)    /* 1568 patches */
#define NSLOT_ (T_*2)        /* 3152 (token,slot) pairs */
#define NCHUNK_ 15

typedef __bf16 bf16x8 __attribute__((ext_vector_type(8)));
typedef float  f32x4  __attribute__((ext_vector_type(4)));

static __device__ __forceinline__ float gelu_f(float x){
    return 0.5f * x * (1.0f + erff(x * 0.70710678118654752440f));
}

static __device__ __forceinline__ unsigned short bf16rne(float x){
    union { float f; unsigned u; } c; c.f = x;
    unsigned u = c.u;
    u += 0x7FFFu + ((u >> 16) & 1u);
    return (unsigned short)(u >> 16);
}

// ---------------- patch gather: x[B,3,224,224] -> pbuf[1568,768] (c,i,j) ----
__global__ void k_patch_gather(const float* __restrict__ x, float* __restrict__ pbuf){
    int idx = blockIdx.x*256 + threadIdx.x;
    if (idx >= TP_*D_) return;
    int k  = idx % D_;
    int tp = idx / D_;
    int p  = tp % NPAT_, b = tp / NPAT_;
    int c  = k >> 8;
    int ij = k & 255;
    int i  = ij >> 4, j = ij & 15;
    int gi = p / GRD_, gj = p % GRD_;
    pbuf[idx] = x[(((size_t)b*CIN_ + c)*IMG_ + gi*PATCH_ + i)*IMG_ + gj*PATCH_ + j];
}

// ---------------- bf16 MFMA GEMM: C[M,N] = act(A@W^T + bias) (+res) ----------
// 128x128 tile, BK=32, 256 threads (4 waves, each 64x64).
// LDS layout per operand: kblock kb in [0,4): region kb*2064 bytes,
// row r at +r*16B, holding bf16 elems k = kb*8 .. kb*8+7 (16B). +16B pad/kb
// breaks the bank aliasing between kblocks. Frag read = ds_read_b128 at
// kb=(lane>>4), row = tile16*16 + (lane&15)  -> 2-way conflict only (free).
template<int ACT, int RES, int GATHER, int MOE>
__global__ __launch_bounds__(256) void k_mgemm(
    const float* __restrict__ A, const int* __restrict__ gidx,
    const float* __restrict__ W, const float* __restrict__ bias,
    const float* __restrict__ res, float* __restrict__ C,
    int M, int N, int K,
    const int* __restrict__ moff, const int* __restrict__ mcnt)
{
    __shared__ __align__(16) char smem[2*8256];
    char* As = smem;
    char* Bs = smem + 8256;
    const int tid = threadIdx.x;
    int row_begin, Mhi;
    if (MOE) {
        const int e = blockIdx.z;
        const int o = moff[e], c = mcnt[e];
        row_begin = o + blockIdx.y*128;
        Mhi = o + c;
        if (row_begin >= Mhi) return;
        W    += (size_t)e*N*K;
        bias += (size_t)e*N;
    } else {
        row_begin = blockIdx.y*128;
        Mhi = M;
    }
    const int bn = blockIdx.x*128;
    const int kc   = (tid & 7)*4;      // this thread's 4-elem k-chunk in [0,32)
    const int mloc = tid >> 3;         // 0..31: row-within-round
    const int wbase = (kc >> 3)*2064 + (kc & 7)*2;
    const float* aP[4];
    const float* wP[4];
    int wOff[4];
    #pragma unroll
    for (int r = 0; r < 4; ++r) {
        const int row = r*32 + mloc;
        wOff[r] = wbase + row*16;
        const int g = row_begin + row;
        const float* ap = nullptr;
        if (g < Mhi) {
            const int tok = GATHER ? (gidx[g] >> 1) : g;
            ap = A + (size_t)tok*K + kc;
        }
        aP[r] = ap;
        wP[r] = W + (size_t)(bn + row)*K + kc;
    }
    const int lane = tid & 63, w = tid >> 6;
    const int wm = (w >> 1)*64, wn = (w & 1)*64;
    const int fr = lane & 15;
    const int rdA = (lane >> 4)*2064 + (wm + fr)*16;
    const int rdB = (lane >> 4)*2064 + (wn + fr)*16;
    f32x4 acc[4][4] = {};
    for (int k0 = 0; k0 < K; k0 += 32) {
        #pragma unroll
        for (int r = 0; r < 4; ++r) {
            float4 v = make_float4(0.f,0.f,0.f,0.f);
            if (aP[r]) { v = *reinterpret_cast<const float4*>(aP[r]); aP[r] += 32; }
            ushort4 h;
            h.x = bf16rne(v.x); h.y = bf16rne(v.y);
            h.z = bf16rne(v.z); h.w = bf16rne(v.w);
            *reinterpret_cast<ushort4*>(As + wOff[r]) = h;
        }
        #pragma unroll
        for (int r = 0; r < 4; ++r) {
            float4 v = *reinterpret_cast<const float4*>(wP[r]); wP[r] += 32;
            ushort4 h;
            h.x = bf16rne(v.x); h.y = bf16rne(v.y);
            h.z = bf16rne(v.z); h.w = bf16rne(v.w);
            *reinterpret_cast<ushort4*>(Bs + wOff[r]) = h;
        }
        __syncthreads();
        bf16x8 af[4], bf[4];
        #pragma unroll
        for (int t = 0; t < 4; ++t) {
            af[t] = *reinterpret_cast<const bf16x8*>(As + rdA + t*256);
            bf[t] = *reinterpret_cast<const bf16x8*>(Bs + rdB + t*256);
        }
        #pragma unroll
        for (int mt = 0; mt < 4; ++mt)
            #pragma unroll
            for (int nt = 0; nt < 4; ++nt)
                acc[mt][nt] = __builtin_amdgcn_mfma_f32_16x16x32_bf16(
                    af[mt], bf[nt], acc[mt][nt], 0, 0, 0);
        __syncthreads();
    }
    const int cr = (lane >> 4)*4;
    #pragma unroll
    for (int nt = 0; nt < 4; ++nt) {
        const int n = bn + wn + nt*16 + fr;
        const float bv = bias[n];
        #pragma unroll
        for (int mt = 0; mt < 4; ++mt) {
            #pragma unroll
            for (int r2 = 0; r2 < 4; ++r2) {
                const int m = row_begin + wm + mt*16 + cr + r2;
                if (m < Mhi) {
                    float v = acc[mt][nt][r2] + bv;
                    if (ACT) v = gelu_f(v);
                    if (RES) v += res[(size_t)m*N + n];
                    C[(size_t)m*N + n] = v;
                }
            }
        }
    }
}

// ---------------- LayerNorm (two-pass, block per row) ------------------------
__global__ __launch_bounds__(256) void k_ln(const float* __restrict__ X,
        const float* __restrict__ w, const float* __restrict__ b,
        float* __restrict__ Y, int in_mul)
{
    const int r = blockIdx.x;
    const float* xr = X + (size_t)r*in_mul*D_;
    float* yr = Y + (size_t)r*D_;
    const int tid = threadIdx.x;
    float v0 = xr[tid], v1 = xr[tid+256], v2 = xr[tid+512];
    __shared__ float red[8];
    const int wid = tid >> 6, lane = tid & 63;
    float s = v0 + v1 + v2;
    for (int m=32;m>0;m>>=1) s += __shfl_xor(s, m);
    if (lane == 0) red[wid] = s;
    __syncthreads();
    if (tid == 0) red[4] = (red[0]+red[1]+red[2]+red[3]) * (1.0f/768.0f);
    __syncthreads();
    const float mean = red[4];
    float d0 = v0-mean, d1 = v1-mean, d2 = v2-mean;
    float q = d0*d0 + d1*d1 + d2*d2;
    for (int m=32;m>0;m>>=1) q += __shfl_xor(q, m);
    if (lane == 0) red[wid] = q;
    __syncthreads();
    if (tid == 0) {
        float var = (red[0]+red[1]+red[2]+red[3]) * (1.0f/768.0f);
        red[5] = 1.0f / sqrtf(var + 1e-5f);
    }
    __syncthreads();
    const float rstd = red[5];
    yr[tid    ] = d0*rstd*w[tid    ] + b[tid    ];
    yr[tid+256] = d1*rstd*w[tid+256] + b[tid+256];
    yr[tid+512] = d2*rstd*w[tid+512] + b[tid+512];
}

// ---------------- fused attention: block per (chunk, head, batch) ------------
__global__ __launch_bounds__(256) void k_attn(const float* __restrict__ qkv,
                                              float* __restrict__ out)
{
    const int chunk = blockIdx.x;
    const int h = blockIdx.y;
    const int b = blockIdx.z;
    const int tid = threadIdx.x;
    __shared__ float Ks[NTOK_][HD_+1];
    __shared__ float qs[HD_];
    __shared__ float ps[NTOK_];
    __shared__ float red[8];
    __shared__ float obuf[4][HD_];
    const size_t basek = (size_t)b*NTOK_*2304 + 768 + h*HD_;
    for (int idx = tid; idx < NTOK_*HD_; idx += 256){
        int m = idx >> 6, d = idx & 63;
        Ks[m][d] = qkv[basek + (size_t)m*2304 + d];
    }
    __syncthreads();
    const int n0 = chunk*14;
    const int n1 = min(n0+14, NTOK_);
    const int wid = tid >> 6, lane = tid & 63;
    for (int n = n0; n < n1; ++n){
        const size_t baseq = (size_t)(b*NTOK_+n)*2304 + h*HD_;
        if (tid < HD_) qs[tid] = qkv[baseq + tid];
        __syncthreads();
        float sc = -3.0e38f;
        if (tid < NTOK_){
            float dot = 0.0f;
            #pragma unroll 8
            for (int d=0; d<HD_; ++d) dot = fmaf(qs[d], Ks[tid][d], dot);
            sc = dot * 0.125f;
        }
        float mv = sc;
        for (int m=32;m>0;m>>=1) mv = fmaxf(mv, __shfl_xor(mv, m));
        if (lane == 0) red[wid] = mv;
        __syncthreads();
        if (tid == 0) red[4] = fmaxf(fmaxf(red[0],red[1]), fmaxf(red[2],red[3]));
        __syncthreads();
        const float mx = red[4];
        float ev = (tid < NTOK_) ? expf(sc - mx) : 0.0f;
        if (tid < NTOK_) ps[tid] = ev;
        float sv = ev;
        for (int m=32;m>0;m>>=1) sv += __shfl_xor(sv, m);
        if (lane == 0) red[wid] = sv;
        __syncthreads();
        if (tid == 0) red[5] = red[0]+red[1]+red[2]+red[3];
        __syncthreads();
        const float inv = 1.0f / red[5];
        const int d = tid & 63, q4 = tid >> 6;
        float acc = 0.0f;
        const size_t basev = (size_t)b*NTOK_*2304 + 1536 + h*HD_ + d;
        for (int m = q4; m < NTOK_; m += 4)
            acc = fmaf(ps[m], qkv[basev + (size_t)m*2304], acc);
        obuf[q4][d] = acc;
        __syncthreads();
        if (tid < HD_){
            float ov = (obuf[0][tid]+obuf[1][tid]+obuf[2][tid]+obuf[3][tid]) * inv;
            out[(size_t)(b*NTOK_+n)*D_ + h*HD_ + tid] = ov;
        }
        __syncthreads();
    }
}

// ---------------- MoE gate: wave per token -----------------------------------
__global__ __launch_bounds__(256) void k_gate(const float* __restrict__ X,
        const float* __restrict__ gw, const float* __restrict__ gb,
        int* __restrict__ t_e, float* __restrict__ t_sc, int* __restrict__ counts)
{
    const int wid = threadIdx.x >> 6, lane = threadIdx.x & 63;
    const int tok = blockIdx.x*4 + wid;
    if (tok >= T_) return;
    float acc[NE_] = {};
    for (int k = lane; k < D_; k += 64){
        float xv = X[(size_t)tok*D_ + k];
        #pragma unroll
        for (int e=0;e<NE_;e++) acc[e] = fmaf(xv, gw[e*D_+k], acc[e]);
    }
    #pragma unroll
    for (int e=0;e<NE_;e++)
        for (int m=32;m>0;m>>=1) acc[e] += __shfl_xor(acc[e], m);
    if (lane == 0){
        float l[NE_];
        #pragma unroll
        for (int e=0;e<NE_;e++) l[e] = acc[e] + gb[e];
        int i0 = 0;
        for (int e=1;e<NE_;e++) if (l[e] > l[i0]) i0 = e;
        int i1 = -1;
        for (int e=0;e<NE_;e++) if (e != i0 && (i1 < 0 || l[e] > l[i1])) i1 = e;
        float e1 = expf(l[i1] - l[i0]);
        float s = 1.0f + e1;
        t_e[tok*2]   = i0;  t_e[tok*2+1]  = i1;
        t_sc[tok*2]  = 1.0f/s; t_sc[tok*2+1] = e1/s;
        atomicAdd(&counts[i0], 1);
        atomicAdd(&counts[i1], 1);
    }
}

__global__ void k_scan(const int* __restrict__ counts, int* __restrict__ off,
                       int* __restrict__ cnt2){
    if (threadIdx.x == 0){
        int s = 0;
        for (int e=0;e<NE_;e++){ off[e] = s; s += counts[e]; cnt2[e] = 0; }
    }
}

__global__ void k_scatter(const int* __restrict__ t_e, const int* __restrict__ off,
                          int* __restrict__ cnt2, int* __restrict__ gidx,
                          int* __restrict__ rg){
    int id = blockIdx.x*256 + threadIdx.x;
    if (id >= NSLOT_) return;
    int e = t_e[id];
    int pos = atomicAdd(&cnt2[e], 1);
    int g = off[e] + pos;
    gidx[g] = id;
    rg[id] = g;
}

__global__ void k_combine(const float* __restrict__ yb, const int* __restrict__ rg,
                          const float* __restrict__ t_sc, float* __restrict__ z){
    int idx = blockIdx.x*256 + threadIdx.x;
    if (idx >= T_*D_) return;
    int t = idx / D_, n = idx % D_;
    int g0 = rg[t*2], g1 = rg[t*2+1];
    z[idx] += t_sc[t*2]*yb[(size_t)g0*D_+n] + t_sc[t*2+1]*yb[(size_t)g1*D_+n];
}

// ---------------- z assembly: cls + pos / patchproj + pos --------------------
__global__ void k_assemble(const float* __restrict__ pe, const float* __restrict__ cls,
                           const float* __restrict__ pos, float* __restrict__ z){
    int idx = blockIdx.x*256 + threadIdx.x;
    if (idx >= T_*D_) return;
    int n = idx % D_, t = idx / D_;
    int b = t / NTOK_, r = t % NTOK_;
    float v;
    if (r == 0) v = cls[n] + pos[n];
    else        v = pe[((size_t)b*NPAT_ + (r-1))*D_ + n] + pos[(size_t)r*D_ + n];
    z[idx] = v;
}

// ---------------- head: wave per class, grid (250, B) ------------------------
__global__ __launch_bounds__(256) void k_head(const float* __restrict__ zn,
        const float* __restrict__ hw, const float* __restrict__ hb,
        float* __restrict__ out)
{
    const int o = blockIdx.x*4 + (threadIdx.x >> 6);
    const int b = blockIdx.y;
    const int lane = threadIdx.x & 63;
    if (o >= NCLS_) return;
    float acc = 0.0f;
    #pragma unroll 4
    for (int k = lane; k < D_; k += 64)
        acc = fmaf(zn[b*D_+k], hw[(size_t)o*D_+k], acc);
    for (int m=32;m>0;m>>=1) acc += __shfl_xor(acc, m);
    if (lane == 0) out[b*NCLS_+o] = acc + hb[o];
}

// =============================================================================
extern "C" void kernel_launch(void* const* d_in, const int* in_sizes, int n_in,
                              void* d_out, int out_size, void* d_ws, size_t ws_size,
                              hipStream_t stream)
{
    const float* x        = (const float*)d_in[0];
    const float* patch_w  = (const float*)d_in[1];
    const float* patch_b  = (const float*)d_in[2];
    const float* cls_tok  = (const float*)d_in[3];
    const float* pos_emb  = (const float*)d_in[4];
    const float* ln1_w    = (const float*)d_in[5];
    const float* ln1_b    = (const float*)d_in[6];
    const float* qkv_w    = (const float*)d_in[7];
    const float* qkv_b    = (const float*)d_in[8];
    const float* proj_w   = (const float*)d_in[9];
    const float* proj_b   = (const float*)d_in[10];
    const float* ln2_w    = (const float*)d_in[11];
    const float* ln2_b    = (const float*)d_in[12];
    const float* fc1_w    = (const float*)d_in[13];
    const float* fc1_b    = (const float*)d_in[14];
    const float* fc2_w    = (const float*)d_in[15];
    const float* fc2_b    = (const float*)d_in[16];
    const float* gate_w   = (const float*)d_in[17];
    const float* gate_b   = (const float*)d_in[18];
    const float* exp_w1   = (const float*)d_in[19];
    const float* exp_b1   = (const float*)d_in[20];
    const float* exp_w2   = (const float*)d_in[21];
    const float* exp_b2   = (const float*)d_in[22];
    const float* norm_w   = (const float*)d_in[23];
    const float* norm_b   = (const float*)d_in[24];
    const float* head_w   = (const float*)d_in[25];
    const float* head_b   = (const float*)d_in[26];

    char* wsb = (char*)d_ws;
    size_t off_ = 0;
    auto alloc = [&](size_t nelem, size_t esz) -> void* {
        void* p = wsb + off_;
        off_ += ((nelem*esz + 255) / 256) * 256;
        return p;
    };
    float* z      = (float*)alloc((size_t)T_*D_, 4);
    float* lnbuf  = (float*)alloc((size_t)T_*D_, 4);
    float* qkvbuf = (float*)alloc((size_t)T_*3*D_, 4);
    float* abuf   = (float*)alloc((size_t)T_*D_, 4);
    float* hid    = (float*)alloc((size_t)NSLOT_*DH_, 4);
    float* yb     = (float*)alloc((size_t)NSLOT_*D_, 4);
    float* t_sc   = (float*)alloc(NSLOT_, 4);
    float* zn     = (float*)alloc((size_t)B_*D_, 4);
    int*   t_e    = (int*)alloc(NSLOT_, 4);
    int*   rg     = (int*)alloc(NSLOT_, 4);
    int*   gidx   = (int*)alloc(NSLOT_, 4);
    int*   counts = (int*)alloc(8, 4);
    int*   offs   = (int*)alloc(8, 4);
    int*   cnt2   = (int*)alloc(8, 4);
    float* pbuf   = hid;

    // ---- patch embedding ----
    k_patch_gather<<<dim3((TP_*D_+255)/256), 256, 0, stream>>>(x, pbuf);
    k_mgemm<0,0,0,0><<<dim3(D_/128, (TP_+127)/128), 256, 0, stream>>>(
        pbuf, nullptr, patch_w, patch_b, nullptr, abuf, TP_, D_, D_, nullptr, nullptr);
    k_assemble<<<dim3((T_*D_+255)/256), 256, 0, stream>>>(abuf, cls_tok, pos_emb, z);

    int di = 0, mi = 0;
    for (int i = 0; i < DEPTH_; ++i){
        k_ln<<<T_, 256, 0, stream>>>(z, ln1_w + i*D_, ln1_b + i*D_, lnbuf, 1);
        k_mgemm<0,0,0,0><<<dim3(3*D_/128, (T_+127)/128), 256, 0, stream>>>(
            lnbuf, nullptr, qkv_w + (size_t)i*3*D_*D_, qkv_b + (size_t)i*3*D_,
            nullptr, qkvbuf, T_, 3*D_, D_, nullptr, nullptr);
        k_attn<<<dim3(NCHUNK_, NH_, B_), 256, 0, stream>>>(qkvbuf, abuf);
        k_mgemm<0,1,0,0><<<dim3(D_/128, (T_+127)/128), 256, 0, stream>>>(
            abuf, nullptr, proj_w + (size_t)i*D_*D_, proj_b + (size_t)i*D_,
            z, z, T_, D_, D_, nullptr, nullptr);
        k_ln<<<T_, 256, 0, stream>>>(z, ln2_w + i*D_, ln2_b + i*D_, lnbuf, 1);
        if (i & 1){ // MoE layers 1,3,5,7,9,11
            hipMemsetAsync(counts, 0, 8*sizeof(int), stream);
            k_gate<<<dim3((T_+3)/4), 256, 0, stream>>>(
                lnbuf, gate_w + (size_t)mi*NE_*D_, gate_b + (size_t)mi*NE_,
                t_e, t_sc, counts);
            k_scan<<<1, 64, 0, stream>>>(counts, offs, cnt2);
            k_scatter<<<dim3((NSLOT_+255)/256), 256, 0, stream>>>(t_e, offs, cnt2, gidx, rg);
            k_mgemm<1,0,1,1><<<dim3(DH_/128, (NSLOT_+127)/128, NE_), 256, 0, stream>>>(
                lnbuf, gidx, exp_w1 + (size_t)mi*NE_*DH_*D_, exp_b1 + (size_t)mi*NE_*DH_,
                nullptr, hid, NSLOT_, DH_, D_, offs, counts);
            k_mgemm<0,0,0,1><<<dim3(D_/128, (NSLOT_+127)/128, NE_), 256, 0, stream>>>(
                hid, nullptr, exp_w2 + (size_t)mi*NE_*D_*DH_, exp_b2 + (size_t)mi*NE_*D_,
                nullptr, yb, NSLOT_, D_, DH_, offs, counts);
            k_combine<<<dim3((T_*D_+255)/256), 256, 0, stream>>>(yb, rg, t_sc, z);
            mi++;
        } else {
            k_mgemm<1,0,0,0><<<dim3(DH_/128, (T_+127)/128), 256, 0, stream>>>(
                lnbuf, nullptr, fc1_w + (size_t)di*DH_*D_, fc1_b + (size_t)di*DH_,
                nullptr, hid, T_, DH_, D_, nullptr, nullptr);
            k_mgemm<0,1,0,0><<<dim3(D_/128, (T_+127)/128), 256, 0, stream>>>(
                hid, nullptr, fc2_w + (size_t)di*D_*DH_, fc2_b + (size_t)di*D_,
                z, z, T_, D_, DH_, nullptr, nullptr);
            di++;
        }
    }
    // ---- final LN on cls tokens only + head ----
    k_ln<<<B_, 256, 0, stream>>>(z, norm_w, norm_b, zn, NTOK_);
    k_head<<<dim3((NCLS_+3)/4, B_), 256, 0, stream>>>(zn, head_w, head_b, (float*)d_out);
}

// Round 3
// 6667.371 us; speedup vs baseline: 3.3386x; 1.2267x over previous
//
#include <hip/hip_runtime.h>
#include <hip/hip_bf16.h>
#include <math.h>

#define B_     8
#define IMG_   224
#define PATCH_ 16
#define CIN_   3
#define D_     768
#define NH_    12
#define DEPTH_ 12
#define NE_    8
#define NCLS_  1000
#define DH_    3072
#define HD_    64
#define GRD_   14
#define NPAT_  196
#define NTOK_  197
#define T_     (B_*NTOK_)    /* 1576 tokens */
#define TP_    (B_*NPAT_)    /* 1568 patches */
#define NSLOT_ (T_*2)        /* 3152 (token,slot) pairs */
#define NCHUNK_ 15

typedef __bf16 bf16_t;
typedef __bf16 bf16x8 __attribute__((ext_vector_type(8)));
typedef __bf16 bf16x4 __attribute__((ext_vector_type(4)));
typedef float  f32x4  __attribute__((ext_vector_type(4)));

static __device__ __forceinline__ float gelu_f(float x){
    return 0.5f * x * (1.0f + erff(x * 0.70710678118654752440f));
}

// ---------------- patch gather: x[B,3,224,224] -> pbuf[1568,768] bf16 -------
__global__ void k_patch_gather(const float* __restrict__ x, bf16_t* __restrict__ pbuf){
    int idx = blockIdx.x*256 + threadIdx.x;
    if (idx >= TP_*D_) return;
    int k  = idx % D_;
    int tp = idx / D_;
    int p  = tp % NPAT_, b = tp / NPAT_;
    int c  = k >> 8;
    int ij = k & 255;
    int i  = ij >> 4, j = ij & 15;
    int gi = p / GRD_, gj = p % GRD_;
    pbuf[idx] = (bf16_t)x[(((size_t)b*CIN_ + c)*IMG_ + gi*PATCH_ + i)*IMG_ + gj*PATCH_ + j];
}

// ---------------- bf16 MFMA GEMM v2 ------------------------------------------
// A bf16 [M][K] (optionally gathered rows), W f32 [N][K], C = act(A@W^T + b)(+res)
// 128x128 tile, BK=64, 256 threads (4 waves x 64x64 output).
// LDS row-major [128][64] bf16 (128B/row), 16B-chunk XOR swizzle c^(row&7):
//   A staged by global_load_lds (linear dest, pre-swizzled per-lane global src),
//   W staged f32->bf16 in-reg (v_cvt_pk) to the same swizzled layout.
// Frag reads ds_read_b128: uniform 8 words/bank (conflict floor).
template<int ACT, int RES, int GATHER, int MOE, int OUTBF>
__global__ __launch_bounds__(256) void k_mgemm(
    const bf16_t* __restrict__ A, const int* __restrict__ gidx,
    const float* __restrict__ W, const float* __restrict__ bias,
    const float* __restrict__ res, void* __restrict__ Cout,
    int M, int N, int K,
    const int* __restrict__ moff, const int* __restrict__ mcnt)
{
    __shared__ __align__(16) bf16_t As[128*64];
    __shared__ __align__(16) bf16_t Bs[128*64];
    const int tid = threadIdx.x, lane = tid & 63, w = tid >> 6;
    int row_begin, Mhi;
    if (MOE) {
        const int e = blockIdx.z;
        const int o = moff[e], c = mcnt[e];
        row_begin = o + blockIdx.y*128;
        Mhi = o + c;
        if (row_begin >= Mhi) return;
        W    += (size_t)e*N*K;
        bias += (size_t)e*N;
    } else {
        row_begin = blockIdx.y*128;
        Mhi = M;
    }
    const int bn = blockIdx.x*128;

    // ---- A staging setup: wave w covers segments s8=w*4..w*4+3 (8 rows each)
    const bf16_t* aG[4];
    #pragma unroll
    for (int i = 0; i < 4; ++i) {
        const int s8 = w*4 + i;
        const int row_l = s8*8 + (lane >> 3);
        const int cc = (lane & 7) ^ (row_l & 7);       // pre-swizzled source chunk
        const int gg = min(row_begin + row_l, Mhi - 1);
        const int tok = GATHER ? (gidx[gg] >> 1) : gg;
        aG[i] = A + (size_t)tok*K + cc*8;
    }
    // ---- W staging setup: thread owns row tid>>1, k-half (tid&1)*32
    const int row_w = tid >> 1, kh = (tid & 1)*32;
    const float* wG = W + (size_t)(bn + row_w)*K + kh;
    int wLds[4];
    #pragma unroll
    for (int j = 0; j < 4; ++j) {
        const int c = (kh >> 3) + j;
        wLds[j] = row_w*128 + ((c ^ (row_w & 7)) << 4);
    }
    // ---- frag read byte offsets
    const int wm = (w >> 1)*64, wn = (w & 1)*64;
    const int fr = lane & 15, kg = lane >> 4;
    int offA[2][4], offB[2][4];
    #pragma unroll
    for (int ks = 0; ks < 2; ++ks)
        #pragma unroll
        for (int t = 0; t < 4; ++t) {
            const int ra = wm + t*16 + fr;
            const int rb = wn + t*16 + fr;
            const int c = ks*4 + kg;
            offA[ks][t] = ra*128 + ((c ^ (ra & 7)) << 4);
            offB[ks][t] = rb*128 + ((c ^ (rb & 7)) << 4);
        }

    f32x4 acc[4][4] = {};
    for (int k0 = 0; k0 < K; k0 += 64) {
        // A: 4 x global_load_lds dwordx4 (wave-uniform dest, per-lane src)
        #pragma unroll
        for (int i = 0; i < 4; ++i) {
            const int s8 = w*4 + i;
            __builtin_amdgcn_global_load_lds(
                (const __attribute__((address_space(1))) void*)(aG[i]),
                (__attribute__((address_space(3))) void*)(&As[s8*512]), 16, 0, 0);
            aG[i] += 64;
        }
        // W: 8 x float4 load -> cvt -> 4 x ds_write_b128 (swizzled)
        float4 wv[8];
        #pragma unroll
        for (int j = 0; j < 8; ++j) wv[j] = *reinterpret_cast<const float4*>(wG + j*4);
        wG += 64;
        #pragma unroll
        for (int j = 0; j < 4; ++j) {
            const float4 u0 = wv[2*j], u1 = wv[2*j+1];
            bf16x8 h;
            h[0]=(bf16_t)u0.x; h[1]=(bf16_t)u0.y; h[2]=(bf16_t)u0.z; h[3]=(bf16_t)u0.w;
            h[4]=(bf16_t)u1.x; h[5]=(bf16_t)u1.y; h[6]=(bf16_t)u1.z; h[7]=(bf16_t)u1.w;
            *reinterpret_cast<bf16x8*>((char*)Bs + wLds[j]) = h;
        }
        __syncthreads();
        #pragma unroll
        for (int ks = 0; ks < 2; ++ks) {
            bf16x8 af[4], bf[4];
            #pragma unroll
            for (int t = 0; t < 4; ++t) {
                af[t] = *reinterpret_cast<const bf16x8*>((const char*)As + offA[ks][t]);
                bf[t] = *reinterpret_cast<const bf16x8*>((const char*)Bs + offB[ks][t]);
            }
            #pragma unroll
            for (int mt = 0; mt < 4; ++mt)
                #pragma unroll
                for (int nt = 0; nt < 4; ++nt)
                    acc[mt][nt] = __builtin_amdgcn_mfma_f32_16x16x32_bf16(
                        af[mt], bf[nt], acc[mt][nt], 0, 0, 0);
        }
        __syncthreads();
    }
    float*  Cf = (float*)Cout;
    bf16_t* Cb = (bf16_t*)Cout;
    const int cr = (lane >> 4)*4;
    #pragma unroll
    for (int nt = 0; nt < 4; ++nt) {
        const int n = bn + wn + nt*16 + fr;
        const float bv = bias[n];
        #pragma unroll
        for (int mt = 0; mt < 4; ++mt) {
            #pragma unroll
            for (int r2 = 0; r2 < 4; ++r2) {
                const int m = row_begin + wm + mt*16 + cr + r2;
                if (m < Mhi) {
                    float v = acc[mt][nt][r2] + bv;
                    if (ACT) v = gelu_f(v);
                    if (RES) v += res[(size_t)m*N + n];
                    if (OUTBF) Cb[(size_t)m*N + n] = (bf16_t)v;
                    else       Cf[(size_t)m*N + n] = v;
                }
            }
        }
    }
}

// ---------------- LayerNorm (two-pass, block per row) ------------------------
template<typename TOUT>
__global__ __launch_bounds__(256) void k_ln(const float* __restrict__ X,
        const float* __restrict__ w, const float* __restrict__ b,
        TOUT* __restrict__ Y, int in_mul)
{
    const int r = blockIdx.x;
    const float* xr = X + (size_t)r*in_mul*D_;
    TOUT* yr = Y + (size_t)r*D_;
    const int tid = threadIdx.x;
    float v0 = xr[tid], v1 = xr[tid+256], v2 = xr[tid+512];
    __shared__ float red[8];
    const int wid = tid >> 6, lane = tid & 63;
    float s = v0 + v1 + v2;
    for (int m=32;m>0;m>>=1) s += __shfl_xor(s, m);
    if (lane == 0) red[wid] = s;
    __syncthreads();
    if (tid == 0) red[4] = (red[0]+red[1]+red[2]+red[3]) * (1.0f/768.0f);
    __syncthreads();
    const float mean = red[4];
    float d0 = v0-mean, d1 = v1-mean, d2 = v2-mean;
    float q = d0*d0 + d1*d1 + d2*d2;
    for (int m=32;m>0;m>>=1) q += __shfl_xor(q, m);
    if (lane == 0) red[wid] = q;
    __syncthreads();
    if (tid == 0) {
        float var = (red[0]+red[1]+red[2]+red[3]) * (1.0f/768.0f);
        red[5] = 1.0f / sqrtf(var + 1e-5f);
    }
    __syncthreads();
    const float rstd = red[5];
    yr[tid    ] = (TOUT)(d0*rstd*w[tid    ] + b[tid    ]);
    yr[tid+256] = (TOUT)(d1*rstd*w[tid+256] + b[tid+256]);
    yr[tid+512] = (TOUT)(d2*rstd*w[tid+512] + b[tid+512]);
}

// ---------------- fused attention (f32 math, bf16 I/O) -----------------------
__global__ __launch_bounds__(256) void k_attn(const bf16_t* __restrict__ qkv,
                                              bf16_t* __restrict__ out)
{
    const int chunk = blockIdx.x;
    const int h = blockIdx.y;
    const int b = blockIdx.z;
    const int tid = threadIdx.x;
    __shared__ float Ks[NTOK_][HD_+1];
    __shared__ float qs[HD_];
    __shared__ float ps[NTOK_];
    __shared__ float red[8];
    __shared__ float obuf[4][HD_];
    const size_t basek = (size_t)b*NTOK_*2304 + 768 + h*HD_;
    for (int idx = tid*4; idx < NTOK_*HD_; idx += 1024){
        int m = idx >> 6, d = idx & 63;
        bf16x4 v = *reinterpret_cast<const bf16x4*>(qkv + basek + (size_t)m*2304 + d);
        Ks[m][d+0] = (float)v[0]; Ks[m][d+1] = (float)v[1];
        Ks[m][d+2] = (float)v[2]; Ks[m][d+3] = (float)v[3];
    }
    __syncthreads();
    const int n0 = chunk*14;
    const int n1 = min(n0+14, NTOK_);
    const int wid = tid >> 6, lane = tid & 63;
    for (int n = n0; n < n1; ++n){
        const size_t baseq = (size_t)(b*NTOK_+n)*2304 + h*HD_;
        if (tid < HD_) qs[tid] = (float)qkv[baseq + tid];
        __syncthreads();
        float sc = -3.0e38f;
        if (tid < NTOK_){
            float dot = 0.0f;
            #pragma unroll 8
            for (int d=0; d<HD_; ++d) dot = fmaf(qs[d], Ks[tid][d], dot);
            sc = dot * 0.125f;
        }
        float mv = sc;
        for (int m=32;m>0;m>>=1) mv = fmaxf(mv, __shfl_xor(mv, m));
        if (lane == 0) red[wid] = mv;
        __syncthreads();
        if (tid == 0) red[4] = fmaxf(fmaxf(red[0],red[1]), fmaxf(red[2],red[3]));
        __syncthreads();
        const float mx = red[4];
        float ev = (tid < NTOK_) ? expf(sc - mx) : 0.0f;
        if (tid < NTOK_) ps[tid] = ev;
        float sv = ev;
        for (int m=32;m>0;m>>=1) sv += __shfl_xor(sv, m);
        if (lane == 0) red[wid] = sv;
        __syncthreads();
        if (tid == 0) red[5] = red[0]+red[1]+red[2]+red[3];
        __syncthreads();
        const float inv = 1.0f / red[5];
        const int d = tid & 63, q4 = tid >> 6;
        float acc = 0.0f;
        const size_t basev = (size_t)b*NTOK_*2304 + 1536 + h*HD_ + d;
        for (int m = q4; m < NTOK_; m += 4)
            acc = fmaf(ps[m], (float)qkv[basev + (size_t)m*2304], acc);
        obuf[q4][d] = acc;
        __syncthreads();
        if (tid < HD_){
            float ov = (obuf[0][tid]+obuf[1][tid]+obuf[2][tid]+obuf[3][tid]) * inv;
            out[(size_t)(b*NTOK_+n)*D_ + h*HD_ + tid] = (bf16_t)ov;
        }
        __syncthreads();
    }
}

// ---------------- MoE gate: wave per token -----------------------------------
__global__ __launch_bounds__(256) void k_gate(const bf16_t* __restrict__ X,
        const float* __restrict__ gw, const float* __restrict__ gb,
        int* __restrict__ t_e, float* __restrict__ t_sc, int* __restrict__ counts)
{
    const int wid = threadIdx.x >> 6, lane = threadIdx.x & 63;
    const int tok = blockIdx.x*4 + wid;
    if (tok >= T_) return;
    float acc[NE_] = {};
    for (int k = lane; k < D_; k += 64){
        float xv = (float)X[(size_t)tok*D_ + k];
        #pragma unroll
        for (int e=0;e<NE_;e++) acc[e] = fmaf(xv, gw[e*D_+k], acc[e]);
    }
    #pragma unroll
    for (int e=0;e<NE_;e++)
        for (int m=32;m>0;m>>=1) acc[e] += __shfl_xor(acc[e], m);
    if (lane == 0){
        float l[NE_];
        #pragma unroll
        for (int e=0;e<NE_;e++) l[e] = acc[e] + gb[e];
        int i0 = 0;
        for (int e=1;e<NE_;e++) if (l[e] > l[i0]) i0 = e;
        int i1 = -1;
        for (int e=0;e<NE_;e++) if (e != i0 && (i1 < 0 || l[e] > l[i1])) i1 = e;
        float e1 = expf(l[i1] - l[i0]);
        float s = 1.0f + e1;
        t_e[tok*2]   = i0;  t_e[tok*2+1]  = i1;
        t_sc[tok*2]  = 1.0f/s; t_sc[tok*2+1] = e1/s;
        atomicAdd(&counts[i0], 1);
        atomicAdd(&counts[i1], 1);
    }
}

__global__ void k_scan(const int* __restrict__ counts, int* __restrict__ off,
                       int* __restrict__ cnt2){
    if (threadIdx.x == 0){
        int s = 0;
        for (int e=0;e<NE_;e++){ off[e] = s; s += counts[e]; cnt2[e] = 0; }
    }
}

__global__ void k_scatter(const int* __restrict__ t_e, const int* __restrict__ off,
                          int* __restrict__ cnt2, int* __restrict__ gidx,
                          int* __restrict__ rg){
    int id = blockIdx.x*256 + threadIdx.x;
    if (id >= NSLOT_) return;
    int e = t_e[id];
    int pos = atomicAdd(&cnt2[e], 1);
    int g = off[e] + pos;
    gidx[g] = id;
    rg[id] = g;
}

__global__ void k_combine(const float* __restrict__ yb, const int* __restrict__ rg,
                          const float* __restrict__ t_sc, float* __restrict__ z){
    int idx = blockIdx.x*256 + threadIdx.x;
    if (idx >= T_*D_) return;
    int t = idx / D_, n = idx % D_;
    int g0 = rg[t*2], g1 = rg[t*2+1];
    z[idx] += t_sc[t*2]*yb[(size_t)g0*D_+n] + t_sc[t*2+1]*yb[(size_t)g1*D_+n];
}

// ---------------- z assembly: cls + pos / patchproj + pos --------------------
__global__ void k_assemble(const float* __restrict__ pe, const float* __restrict__ cls,
                           const float* __restrict__ pos, float* __restrict__ z){
    int idx = blockIdx.x*256 + threadIdx.x;
    if (idx >= T_*D_) return;
    int n = idx % D_, t = idx / D_;
    int b = t / NTOK_, r = t % NTOK_;
    float v;
    if (r == 0) v = cls[n] + pos[n];
    else        v = pe[((size_t)b*NPAT_ + (r-1))*D_ + n] + pos[(size_t)r*D_ + n];
    z[idx] = v;
}

// ---------------- head: wave per class, grid (250, B) ------------------------
__global__ __launch_bounds__(256) void k_head(const float* __restrict__ zn,
        const float* __restrict__ hw, const float* __restrict__ hb,
        float* __restrict__ out)
{
    const int o = blockIdx.x*4 + (threadIdx.x >> 6);
    const int b = blockIdx.y;
    const int lane = threadIdx.x & 63;
    if (o >= NCLS_) return;
    float acc = 0.0f;
    #pragma unroll 4
    for (int k = lane; k < D_; k += 64)
        acc = fmaf(zn[b*D_+k], hw[(size_t)o*D_+k], acc);
    for (int m=32;m>0;m>>=1) acc += __shfl_xor(acc, m);
    if (lane == 0) out[b*NCLS_+o] = acc + hb[o];
}

// =============================================================================
extern "C" void kernel_launch(void* const* d_in, const int* in_sizes, int n_in,
                              void* d_out, int out_size, void* d_ws, size_t ws_size,
                              hipStream_t stream)
{
    const float* x        = (const float*)d_in[0];
    const float* patch_w  = (const float*)d_in[1];
    const float* patch_b  = (const float*)d_in[2];
    const float* cls_tok  = (const float*)d_in[3];
    const float* pos_emb  = (const float*)d_in[4];
    const float* ln1_w    = (const float*)d_in[5];
    const float* ln1_b    = (const float*)d_in[6];
    const float* qkv_w    = (const float*)d_in[7];
    const float* qkv_b    = (const float*)d_in[8];
    const float* proj_w   = (const float*)d_in[9];
    const float* proj_b   = (const float*)d_in[10];
    const float* ln2_w    = (const float*)d_in[11];
    const float* ln2_b    = (const float*)d_in[12];
    const float* fc1_w    = (const float*)d_in[13];
    const float* fc1_b    = (const float*)d_in[14];
    const float* fc2_w    = (const float*)d_in[15];
    const float* fc2_b    = (const float*)d_in[16];
    const float* gate_w   = (const float*)d_in[17];
    const float* gate_b   = (const float*)d_in[18];
    const float* exp_w1   = (const float*)d_in[19];
    const float* exp_b1   = (const float*)d_in[20];
    const float* exp_w2   = (const float*)d_in[21];
    const float* exp_b2   = (const float*)d_in[22];
    const float* norm_w   = (const float*)d_in[23];
    const float* norm_b   = (const float*)d_in[24];
    const float* head_w   = (const float*)d_in[25];
    const float* head_b   = (const float*)d_in[26];

    char* wsb = (char*)d_ws;
    size_t off_ = 0;
    auto alloc = [&](size_t nelem, size_t esz) -> void* {
        void* p = wsb + off_;
        off_ += ((nelem*esz + 255) / 256) * 256;
        return p;
    };
    float*  z      = (float*) alloc((size_t)T_*D_, 4);
    bf16_t* lnbuf  = (bf16_t*)alloc((size_t)T_*D_, 2);
    bf16_t* qkvbuf = (bf16_t*)alloc((size_t)T_*3*D_, 2);
    bf16_t* abuf   = (bf16_t*)alloc((size_t)T_*D_, 2);
    bf16_t* hid    = (bf16_t*)alloc((size_t)NSLOT_*DH_, 2);
    float*  yb     = (float*) alloc((size_t)NSLOT_*D_, 4);
    float*  t_sc   = (float*) alloc(NSLOT_, 4);
    float*  zn     = (float*) alloc((size_t)B_*D_, 4);
    int*    t_e    = (int*)   alloc(NSLOT_, 4);
    int*    rg     = (int*)   alloc(NSLOT_, 4);
    int*    gidx   = (int*)   alloc(NSLOT_, 4);
    int*    counts = (int*)   alloc(8, 4);
    int*    offs   = (int*)   alloc(8, 4);
    int*    cnt2   = (int*)   alloc(8, 4);
    bf16_t* pbuf   = hid;      // patch staging, dead before fc1 first writes hid
    float*  pout   = yb;       // patch-proj f32 out, dead before MoE writes yb

    // ---- patch embedding ----
    k_patch_gather<<<dim3((TP_*D_+255)/256), 256, 0, stream>>>(x, pbuf);
    k_mgemm<0,0,0,0,0><<<dim3(D_/128, 13), 256, 0, stream>>>(
        pbuf, nullptr, patch_w, patch_b, nullptr, pout, TP_, D_, D_, nullptr, nullptr);
    k_assemble<<<dim3((T_*D_+255)/256), 256, 0, stream>>>(pout, cls_tok, pos_emb, z);

    int di = 0, mi = 0;
    for (int i = 0; i < DEPTH_; ++i){
        k_ln<bf16_t><<<T_, 256, 0, stream>>>(z, ln1_w + i*D_, ln1_b + i*D_, lnbuf, 1);
        k_mgemm<0,0,0,0,1><<<dim3(3*D_/128, 13), 256, 0, stream>>>(
            lnbuf, nullptr, qkv_w + (size_t)i*3*D_*D_, qkv_b + (size_t)i*3*D_,
            nullptr, qkvbuf, T_, 3*D_, D_, nullptr, nullptr);
        k_attn<<<dim3(NCHUNK_, NH_, B_), 256, 0, stream>>>(qkvbuf, abuf);
        k_mgemm<0,1,0,0,0><<<dim3(D_/128, 13), 256, 0, stream>>>(
            abuf, nullptr, proj_w + (size_t)i*D_*D_, proj_b + (size_t)i*D_,
            z, z, T_, D_, D_, nullptr, nullptr);
        k_ln<bf16_t><<<T_, 256, 0, stream>>>(z, ln2_w + i*D_, ln2_b + i*D_, lnbuf, 1);
        if (i & 1){ // MoE layers 1,3,5,7,9,11
            hipMemsetAsync(counts, 0, 8*sizeof(int), stream);
            k_gate<<<dim3((T_+3)/4), 256, 0, stream>>>(
                lnbuf, gate_w + (size_t)mi*NE_*D_, gate_b + (size_t)mi*NE_,
                t_e, t_sc, counts);
            k_scan<<<1, 64, 0, stream>>>(counts, offs, cnt2);
            k_scatter<<<dim3((NSLOT_+255)/256), 256, 0, stream>>>(t_e, offs, cnt2, gidx, rg);
            k_mgemm<1,0,1,1,1><<<dim3(DH_/128, 13, NE_), 256, 0, stream>>>(
                lnbuf, gidx, exp_w1 + (size_t)mi*NE_*DH_*D_, exp_b1 + (size_t)mi*NE_*DH_,
                nullptr, hid, NSLOT_, DH_, D_, offs, counts);
            k_mgemm<0,0,0,1,0><<<dim3(D_/128, 13, NE_), 256, 0, stream>>>(
                hid, nullptr, exp_w2 + (size_t)mi*NE_*D_*DH_, exp_b2 + (size_t)mi*NE_*D_,
                nullptr, yb, NSLOT_, D_, DH_, offs, counts);
            k_combine<<<dim3((T_*D_+255)/256), 256, 0, stream>>>(yb, rg, t_sc, z);
            mi++;
        } else {
            k_mgemm<1,0,0,0,1><<<dim3(DH_/128, 13), 256, 0, stream>>>(
                lnbuf, nullptr, fc1_w + (size_t)di*DH_*D_, fc1_b + (size_t)di*DH_,
                nullptr, hid, T_, DH_, D_, nullptr, nullptr);
            k_mgemm<0,1,0,0,0><<<dim3(D_/128, 13), 256, 0, stream>>>(
                hid, nullptr, fc2_w + (size_t)di*D_*DH_, fc2_b + (size_t)di*D_,
                z, z, T_, D_, DH_, nullptr, nullptr);
            di++;
        }
    }
    // ---- final LN on cls tokens only + head ----
    k_ln<float><<<B_, 256, 0, stream>>>(z, norm_w, norm_b, zn, NTOK_);
    k_head<<<dim3((NCLS_+3)/4, B_), 256, 0, stream>>>(zn, head_w, head_b, (float*)d_out);
}

// Round 4
// 5805.428 us; speedup vs baseline: 3.8342x; 1.1485x over previous
//
#include <hip/hip_runtime.h>
#include <hip/hip_bf16.h>
#include <math.h>

#define B_     8
#define IMG_   224
#define PATCH_ 16
#define CIN_   3
#define D_     768
#define NH_    12
#define DEPTH_ 12
#define NE_    8
#define NCLS_  1000
#define DH_    3072
#define HD_    64
#define GRD_   14
#define NPAT_  196
#define NTOK_  197
#define T_     (B_*NTOK_)    /* 1576 tokens */
#define TP_    (B_*NPAT_)    /* 1568 patches */
#define NSLOT_ (T_*2)        /* 3152 (token,slot) pairs */
#define NCHUNK_ 15

typedef __bf16 bf16_t;
typedef __bf16 bf16x8 __attribute__((ext_vector_type(8)));
typedef __bf16 bf16x4 __attribute__((ext_vector_type(4)));
typedef float  f32x4  __attribute__((ext_vector_type(4)));

static __device__ __forceinline__ float gelu_f(float x){
    return 0.5f * x * (1.0f + erff(x * 0.70710678118654752440f));
}

// ---------------- f32 -> bf16 bulk convert (8 elems/thread) ------------------
__global__ __launch_bounds__(256) void k_cvt(const float* __restrict__ in,
                                             bf16_t* __restrict__ out, int n){
    int i = (blockIdx.x*256 + threadIdx.x)*8;
    if (i >= n) return;
    float4 a = *reinterpret_cast<const float4*>(in + i);
    float4 b = *reinterpret_cast<const float4*>(in + i + 4);
    bf16x8 h;
    h[0]=(bf16_t)a.x; h[1]=(bf16_t)a.y; h[2]=(bf16_t)a.z; h[3]=(bf16_t)a.w;
    h[4]=(bf16_t)b.x; h[5]=(bf16_t)b.y; h[6]=(bf16_t)b.z; h[7]=(bf16_t)b.w;
    *reinterpret_cast<bf16x8*>(out + i) = h;
}

// ---------------- patch gather: x[B,3,224,224] -> pbuf[1568,768] bf16 -------
__global__ void k_patch_gather(const float* __restrict__ x, bf16_t* __restrict__ pbuf){
    int idx = blockIdx.x*256 + threadIdx.x;
    if (idx >= TP_*D_) return;
    int k  = idx % D_;
    int tp = idx / D_;
    int p  = tp % NPAT_, b = tp / NPAT_;
    int c  = k >> 8;
    int ij = k & 255;
    int i  = ij >> 4, j = ij & 15;
    int gi = p / GRD_, gj = p % GRD_;
    pbuf[idx] = (bf16_t)x[(((size_t)b*CIN_ + c)*IMG_ + gi*PATCH_ + i)*IMG_ + gj*PATCH_ + j];
}

// ---------------- bf16 MFMA GEMM v3 ------------------------------------------
// A bf16 [M][K] (opt. gathered rows), W bf16 [N][K], C = act(A@W^T + b)(+res)
// 128x128 tile, BK=64, 256 threads (4 waves x 64x64 output).
// Both operands staged via global_load_lds dwordx4 (linear LDS dest,
// pre-swizzled per-lane global source, XOR chunk^(row&7)); double-buffered
// with next-tile prefetch issued before compute (T3-minimum 2-phase):
//   STAGE(0); sync; for t { if(t+1<nt) STAGE(t+1); compute(t); sync; }
template<int ACT, int RES, int GATHER, int MOE, int OUTBF>
__global__ __launch_bounds__(256) void k_mgemm(
    const bf16_t* __restrict__ A, const int* __restrict__ gidx,
    const bf16_t* __restrict__ W, const float* __restrict__ bias,
    const float* __restrict__ res, void* __restrict__ Cout,
    int M, int N, int K,
    const int* __restrict__ moff, const int* __restrict__ mcnt)
{
    __shared__ __align__(16) bf16_t As[2][128*64];
    __shared__ __align__(16) bf16_t Bs[2][128*64];
    const int tid = threadIdx.x, lane = tid & 63, w = tid >> 6;
    int row_begin, Mhi;
    if (MOE) {
        const int e = blockIdx.z;
        const int o = moff[e], c = mcnt[e];
        row_begin = o + blockIdx.y*128;
        Mhi = o + c;
        if (row_begin >= Mhi) return;
        W    += (size_t)e*N*K;
        bias += (size_t)e*N;
    } else {
        row_begin = blockIdx.y*128;
        Mhi = M;
    }
    const int bn = blockIdx.x*128;

    // staging: wave w owns 8-row segments s8 = w*4 .. w*4+3 of both tiles
    const bf16_t* aG[4];
    const bf16_t* wG[4];
    int ldsOff[4];
    #pragma unroll
    for (int i = 0; i < 4; ++i) {
        const int s8 = w*4 + i;
        const int row_l = s8*8 + (lane >> 3);
        const int cc = (lane & 7) ^ (row_l & 7);       // pre-swizzled source chunk
        const int gg = min(row_begin + row_l, Mhi - 1);
        const int tok = GATHER ? (gidx[gg] >> 1) : gg;
        aG[i] = A + (size_t)tok*K + cc*8;
        wG[i] = W + (size_t)(bn + row_l)*K + cc*8;
        ldsOff[i] = s8*512;                            // elems: 8 rows x 64
    }
    // frag read byte offsets (within one 16KB buffer)
    const int wm = (w >> 1)*64, wn = (w & 1)*64;
    const int fr = lane & 15, kg = lane >> 4;
    int offA[2][4], offB[2][4];
    #pragma unroll
    for (int ks = 0; ks < 2; ++ks)
        #pragma unroll
        for (int t = 0; t < 4; ++t) {
            const int ra = wm + t*16 + fr;
            const int rb = wn + t*16 + fr;
            const int c = ks*4 + kg;
            offA[ks][t] = ra*128 + ((c ^ (ra & 7)) << 4);
            offB[ks][t] = rb*128 + ((c ^ (rb & 7)) << 4);
        }

    f32x4 acc[4][4] = {};
    const int nt = K >> 6;
    int cur = 0;
    // prologue stage of tile 0
    #pragma unroll
    for (int i = 0; i < 4; ++i) {
        __builtin_amdgcn_global_load_lds(
            (const __attribute__((address_space(1))) void*)(aG[i]),
            (__attribute__((address_space(3))) void*)(&As[0][ldsOff[i]]), 16, 0, 0);
        aG[i] += 64;
        __builtin_amdgcn_global_load_lds(
            (const __attribute__((address_space(1))) void*)(wG[i]),
            (__attribute__((address_space(3))) void*)(&Bs[0][ldsOff[i]]), 16, 0, 0);
        wG[i] += 64;
    }
    __syncthreads();
    for (int t = 0; t < nt; ++t) {
        if (t + 1 < nt) {
            const int nb = cur ^ 1;
            #pragma unroll
            for (int i = 0; i < 4; ++i) {
                __builtin_amdgcn_global_load_lds(
                    (const __attribute__((address_space(1))) void*)(aG[i]),
                    (__attribute__((address_space(3))) void*)(&As[nb][ldsOff[i]]), 16, 0, 0);
                aG[i] += 64;
                __builtin_amdgcn_global_load_lds(
                    (const __attribute__((address_space(1))) void*)(wG[i]),
                    (__attribute__((address_space(3))) void*)(&Bs[nb][ldsOff[i]]), 16, 0, 0);
                wG[i] += 64;
            }
        }
        const char* baseA = (const char*)&As[cur][0];
        const char* baseB = (const char*)&Bs[cur][0];
        #pragma unroll
        for (int ks = 0; ks < 2; ++ks) {
            bf16x8 af[4], bf[4];
            #pragma unroll
            for (int t2 = 0; t2 < 4; ++t2) {
                af[t2] = *reinterpret_cast<const bf16x8*>(baseA + offA[ks][t2]);
                bf[t2] = *reinterpret_cast<const bf16x8*>(baseB + offB[ks][t2]);
            }
            #pragma unroll
            for (int mt = 0; mt < 4; ++mt)
                #pragma unroll
                for (int nt2 = 0; nt2 < 4; ++nt2)
                    acc[mt][nt2] = __builtin_amdgcn_mfma_f32_16x16x32_bf16(
                        af[mt], bf[nt2], acc[mt][nt2], 0, 0, 0);
        }
        __syncthreads();   // drains prefetch (vmcnt 0) + all waves done reading
        cur ^= 1;
    }
    float*  Cf = (float*)Cout;
    bf16_t* Cb = (bf16_t*)Cout;
    const int cr = (lane >> 4)*4;
    #pragma unroll
    for (int nt2 = 0; nt2 < 4; ++nt2) {
        const int n = bn + wn + nt2*16 + fr;
        const float bv = bias[n];
        #pragma unroll
        for (int mt = 0; mt < 4; ++mt) {
            #pragma unroll
            for (int r2 = 0; r2 < 4; ++r2) {
                const int m = row_begin + wm + mt*16 + cr + r2;
                if (m < Mhi) {
                    float v = acc[mt][nt2][r2] + bv;
                    if (ACT) v = gelu_f(v);
                    if (RES) v += res[(size_t)m*N + n];
                    if (OUTBF) Cb[(size_t)m*N + n] = (bf16_t)v;
                    else       Cf[(size_t)m*N + n] = v;
                }
            }
        }
    }
}

// ---------------- LayerNorm (two-pass, block per row) ------------------------
template<typename TOUT>
__global__ __launch_bounds__(256) void k_ln(const float* __restrict__ X,
        const float* __restrict__ w, const float* __restrict__ b,
        TOUT* __restrict__ Y, int in_mul)
{
    const int r = blockIdx.x;
    const float* xr = X + (size_t)r*in_mul*D_;
    TOUT* yr = Y + (size_t)r*D_;
    const int tid = threadIdx.x;
    float v0 = xr[tid], v1 = xr[tid+256], v2 = xr[tid+512];
    __shared__ float red[8];
    const int wid = tid >> 6, lane = tid & 63;
    float s = v0 + v1 + v2;
    for (int m=32;m>0;m>>=1) s += __shfl_xor(s, m);
    if (lane == 0) red[wid] = s;
    __syncthreads();
    if (tid == 0) red[4] = (red[0]+red[1]+red[2]+red[3]) * (1.0f/768.0f);
    __syncthreads();
    const float mean = red[4];
    float d0 = v0-mean, d1 = v1-mean, d2 = v2-mean;
    float q = d0*d0 + d1*d1 + d2*d2;
    for (int m=32;m>0;m>>=1) q += __shfl_xor(q, m);
    if (lane == 0) red[wid] = q;
    __syncthreads();
    if (tid == 0) {
        float var = (red[0]+red[1]+red[2]+red[3]) * (1.0f/768.0f);
        red[5] = 1.0f / sqrtf(var + 1e-5f);
    }
    __syncthreads();
    const float rstd = red[5];
    yr[tid    ] = (TOUT)(d0*rstd*w[tid    ] + b[tid    ]);
    yr[tid+256] = (TOUT)(d1*rstd*w[tid+256] + b[tid+256]);
    yr[tid+512] = (TOUT)(d2*rstd*w[tid+512] + b[tid+512]);
}

// ---------------- fused attention (f32 math, bf16 I/O) -----------------------
__global__ __launch_bounds__(256) void k_attn(const bf16_t* __restrict__ qkv,
                                              bf16_t* __restrict__ out)
{
    const int chunk = blockIdx.x;
    const int h = blockIdx.y;
    const int b = blockIdx.z;
    const int tid = threadIdx.x;
    __shared__ float Ks[NTOK_][HD_+1];
    __shared__ float qs[HD_];
    __shared__ float ps[NTOK_];
    __shared__ float red[8];
    __shared__ float obuf[4][HD_];
    const size_t basek = (size_t)b*NTOK_*2304 + 768 + h*HD_;
    for (int idx = tid*4; idx < NTOK_*HD_; idx += 1024){
        int m = idx >> 6, d = idx & 63;
        bf16x4 v = *reinterpret_cast<const bf16x4*>(qkv + basek + (size_t)m*2304 + d);
        Ks[m][d+0] = (float)v[0]; Ks[m][d+1] = (float)v[1];
        Ks[m][d+2] = (float)v[2]; Ks[m][d+3] = (float)v[3];
    }
    __syncthreads();
    const int n0 = chunk*14;
    const int n1 = min(n0+14, NTOK_);
    const int wid = tid >> 6, lane = tid & 63;
    for (int n = n0; n < n1; ++n){
        const size_t baseq = (size_t)(b*NTOK_+n)*2304 + h*HD_;
        if (tid < HD_) qs[tid] = (float)qkv[baseq + tid];
        __syncthreads();
        float sc = -3.0e38f;
        if (tid < NTOK_){
            float dot = 0.0f;
            #pragma unroll 8
            for (int d=0; d<HD_; ++d) dot = fmaf(qs[d], Ks[tid][d], dot);
            sc = dot * 0.125f;
        }
        float mv = sc;
        for (int m=32;m>0;m>>=1) mv = fmaxf(mv, __shfl_xor(mv, m));
        if (lane == 0) red[wid] = mv;
        __syncthreads();
        if (tid == 0) red[4] = fmaxf(fmaxf(red[0],red[1]), fmaxf(red[2],red[3]));
        __syncthreads();
        const float mx = red[4];
        float ev = (tid < NTOK_) ? expf(sc - mx) : 0.0f;
        if (tid < NTOK_) ps[tid] = ev;
        float sv = ev;
        for (int m=32;m>0;m>>=1) sv += __shfl_xor(sv, m);
        if (lane == 0) red[wid] = sv;
        __syncthreads();
        if (tid == 0) red[5] = red[0]+red[1]+red[2]+red[3];
        __syncthreads();
        const float inv = 1.0f / red[5];
        const int d = tid & 63, q4 = tid >> 6;
        float acc = 0.0f;
        const size_t basev = (size_t)b*NTOK_*2304 + 1536 + h*HD_ + d;
        for (int m = q4; m < NTOK_; m += 4)
            acc = fmaf(ps[m], (float)qkv[basev + (size_t)m*2304], acc);
        obuf[q4][d] = acc;
        __syncthreads();
        if (tid < HD_){
            float ov = (obuf[0][tid]+obuf[1][tid]+obuf[2][tid]+obuf[3][tid]) * inv;
            out[(size_t)(b*NTOK_+n)*D_ + h*HD_ + tid] = (bf16_t)ov;
        }
        __syncthreads();
    }
}

// ---------------- MoE gate: wave per token -----------------------------------
__global__ __launch_bounds__(256) void k_gate(const bf16_t* __restrict__ X,
        const float* __restrict__ gw, const float* __restrict__ gb,
        int* __restrict__ t_e, float* __restrict__ t_sc, int* __restrict__ counts)
{
    const int wid = threadIdx.x >> 6, lane = threadIdx.x & 63;
    const int tok = blockIdx.x*4 + wid;
    if (tok >= T_) return;
    float acc[NE_] = {};
    for (int k = lane; k < D_; k += 64){
        float xv = (float)X[(size_t)tok*D_ + k];
        #pragma unroll
        for (int e=0;e<NE_;e++) acc[e] = fmaf(xv, gw[e*D_+k], acc[e]);
    }
    #pragma unroll
    for (int e=0;e<NE_;e++)
        for (int m=32;m>0;m>>=1) acc[e] += __shfl_xor(acc[e], m);
    if (lane == 0){
        float l[NE_];
        #pragma unroll
        for (int e=0;e<NE_;e++) l[e] = acc[e] + gb[e];
        int i0 = 0;
        for (int e=1;e<NE_;e++) if (l[e] > l[i0]) i0 = e;
        int i1 = -1;
        for (int e=0;e<NE_;e++) if (e != i0 && (i1 < 0 || l[e] > l[i1])) i1 = e;
        float e1 = expf(l[i1] - l[i0]);
        float s = 1.0f + e1;
        t_e[tok*2]   = i0;  t_e[tok*2+1]  = i1;
        t_sc[tok*2]  = 1.0f/s; t_sc[tok*2+1] = e1/s;
        atomicAdd(&counts[i0], 1);
        atomicAdd(&counts[i1], 1);
    }
}

__global__ void k_scan(const int* __restrict__ counts, int* __restrict__ off,
                       int* __restrict__ cnt2){
    if (threadIdx.x == 0){
        int s = 0;
        for (int e=0;e<NE_;e++){ off[e] = s; s += counts[e]; cnt2[e] = 0; }
    }
}

__global__ void k_scatter(const int* __restrict__ t_e, const int* __restrict__ off,
                          int* __restrict__ cnt2, int* __restrict__ gidx,
                          int* __restrict__ rg){
    int id = blockIdx.x*256 + threadIdx.x;
    if (id >= NSLOT_) return;
    int e = t_e[id];
    int pos = atomicAdd(&cnt2[e], 1);
    int g = off[e] + pos;
    gidx[g] = id;
    rg[id] = g;
}

__global__ void k_combine(const float* __restrict__ yb, const int* __restrict__ rg,
                          const float* __restrict__ t_sc, float* __restrict__ z){
    int idx = blockIdx.x*256 + threadIdx.x;
    if (idx >= T_*D_) return;
    int t = idx / D_, n = idx % D_;
    int g0 = rg[t*2], g1 = rg[t*2+1];
    z[idx] += t_sc[t*2]*yb[(size_t)g0*D_+n] + t_sc[t*2+1]*yb[(size_t)g1*D_+n];
}

// ---------------- z assembly: cls + pos / patchproj + pos --------------------
__global__ void k_assemble(const float* __restrict__ pe, const float* __restrict__ cls,
                           const float* __restrict__ pos, float* __restrict__ z){
    int idx = blockIdx.x*256 + threadIdx.x;
    if (idx >= T_*D_) return;
    int n = idx % D_, t = idx / D_;
    int b = t / NTOK_, r = t % NTOK_;
    float v;
    if (r == 0) v = cls[n] + pos[n];
    else        v = pe[((size_t)b*NPAT_ + (r-1))*D_ + n] + pos[(size_t)r*D_ + n];
    z[idx] = v;
}

// ---------------- head: wave per class, grid (250, B) ------------------------
__global__ __launch_bounds__(256) void k_head(const float* __restrict__ zn,
        const float* __restrict__ hw, const float* __restrict__ hb,
        float* __restrict__ out)
{
    const int o = blockIdx.x*4 + (threadIdx.x >> 6);
    const int b = blockIdx.y;
    const int lane = threadIdx.x & 63;
    if (o >= NCLS_) return;
    float acc = 0.0f;
    #pragma unroll 4
    for (int k = lane; k < D_; k += 64)
        acc = fmaf(zn[b*D_+k], hw[(size_t)o*D_+k], acc);
    for (int m=32;m>0;m>>=1) acc += __shfl_xor(acc, m);
    if (lane == 0) out[b*NCLS_+o] = acc + hb[o];
}

// =============================================================================
extern "C" void kernel_launch(void* const* d_in, const int* in_sizes, int n_in,
                              void* d_out, int out_size, void* d_ws, size_t ws_size,
                              hipStream_t stream)
{
    const float* x        = (const float*)d_in[0];
    const float* patch_w  = (const float*)d_in[1];
    const float* patch_b  = (const float*)d_in[2];
    const float* cls_tok  = (const float*)d_in[3];
    const float* pos_emb  = (const float*)d_in[4];
    const float* ln1_w    = (const float*)d_in[5];
    const float* ln1_b    = (const float*)d_in[6];
    const float* qkv_w    = (const float*)d_in[7];
    const float* qkv_b    = (const float*)d_in[8];
    const float* proj_w   = (const float*)d_in[9];
    const float* proj_b   = (const float*)d_in[10];
    const float* ln2_w    = (const float*)d_in[11];
    const float* ln2_b    = (const float*)d_in[12];
    const float* fc1_w    = (const float*)d_in[13];
    const float* fc1_b    = (const float*)d_in[14];
    const float* fc2_w    = (const float*)d_in[15];
    const float* fc2_b    = (const float*)d_in[16];
    const float* gate_w   = (const float*)d_in[17];
    const float* gate_b   = (const float*)d_in[18];
    const float* exp_w1   = (const float*)d_in[19];
    const float* exp_b1   = (const float*)d_in[20];
    const float* exp_w2   = (const float*)d_in[21];
    const float* exp_b2   = (const float*)d_in[22];
    const float* norm_w   = (const float*)d_in[23];
    const float* norm_b   = (const float*)d_in[24];
    const float* head_w   = (const float*)d_in[25];
    const float* head_b   = (const float*)d_in[26];

    char* wsb = (char*)d_ws;
    size_t off_ = 0;
    auto alloc = [&](size_t nelem, size_t esz) -> void* {
        void* p = wsb + off_;
        off_ += ((nelem*esz + 255) / 256) * 256;
        return p;
    };
    float*  z      = (float*) alloc((size_t)T_*D_, 4);
    bf16_t* lnbuf  = (bf16_t*)alloc((size_t)T_*D_, 2);
    bf16_t* qkvbuf = (bf16_t*)alloc((size_t)T_*3*D_, 2);
    bf16_t* abuf   = (bf16_t*)alloc((size_t)T_*D_, 2);
    bf16_t* hid    = (bf16_t*)alloc((size_t)NSLOT_*DH_, 2);
    float*  yb     = (float*) alloc((size_t)NSLOT_*D_, 4);
    float*  t_sc   = (float*) alloc(NSLOT_, 4);
    float*  zn     = (float*) alloc((size_t)B_*D_, 4);
    int*    t_e    = (int*)   alloc(NSLOT_, 4);
    int*    rg     = (int*)   alloc(NSLOT_, 4);
    int*    gidx   = (int*)   alloc(NSLOT_, 4);
    int*    counts = (int*)   alloc(8, 4);
    int*    offs   = (int*)   alloc(8, 4);
    int*    cnt2   = (int*)   alloc(8, 4);
    // bf16 weight copies
    const size_t n_patch = (size_t)D_*D_;
    const size_t n_qkv   = (size_t)DEPTH_*3*D_*D_;
    const size_t n_proj  = (size_t)DEPTH_*D_*D_;
    const size_t n_fc1   = (size_t)6*DH_*D_;
    const size_t n_fc2   = (size_t)6*D_*DH_;
    const size_t n_e1    = (size_t)6*NE_*DH_*D_;
    const size_t n_e2    = (size_t)6*NE_*D_*DH_;
    bf16_t* wb_patch = (bf16_t*)alloc(n_patch, 2);
    bf16_t* wb_qkv   = (bf16_t*)alloc(n_qkv, 2);
    bf16_t* wb_proj  = (bf16_t*)alloc(n_proj, 2);
    bf16_t* wb_fc1   = (bf16_t*)alloc(n_fc1, 2);
    bf16_t* wb_fc2   = (bf16_t*)alloc(n_fc2, 2);
    bf16_t* wb_e1    = (bf16_t*)alloc(n_e1, 2);
    bf16_t* wb_e2    = (bf16_t*)alloc(n_e2, 2);
    bf16_t* pbuf   = hid;      // patch staging, dead before fc1 first writes hid
    float*  pout   = yb;       // patch-proj f32 out, dead before MoE writes yb

    // ---- weight pre-convert (f32 -> bf16), ~567 MB total --------------------
    auto cvt = [&](const float* src, bf16_t* dst, size_t n){
        k_cvt<<<dim3((unsigned)((n/8 + 255)/256)), 256, 0, stream>>>(src, dst, (int)n);
    };
    cvt(patch_w, wb_patch, n_patch);
    cvt(qkv_w,   wb_qkv,   n_qkv);
    cvt(proj_w,  wb_proj,  n_proj);
    cvt(fc1_w,   wb_fc1,   n_fc1);
    cvt(fc2_w,   wb_fc2,   n_fc2);
    cvt(exp_w1,  wb_e1,    n_e1);
    cvt(exp_w2,  wb_e2,    n_e2);

    // ---- patch embedding ----
    k_patch_gather<<<dim3((TP_*D_+255)/256), 256, 0, stream>>>(x, pbuf);
    k_mgemm<0,0,0,0,0><<<dim3(D_/128, 13), 256, 0, stream>>>(
        pbuf, nullptr, wb_patch, patch_b, nullptr, pout, TP_, D_, D_, nullptr, nullptr);
    k_assemble<<<dim3((T_*D_+255)/256), 256, 0, stream>>>(pout, cls_tok, pos_emb, z);

    int di = 0, mi = 0;
    for (int i = 0; i < DEPTH_; ++i){
        k_ln<bf16_t><<<T_, 256, 0, stream>>>(z, ln1_w + i*D_, ln1_b + i*D_, lnbuf, 1);
        k_mgemm<0,0,0,0,1><<<dim3(3*D_/128, 13), 256, 0, stream>>>(
            lnbuf, nullptr, wb_qkv + (size_t)i*3*D_*D_, qkv_b + (size_t)i*3*D_,
            nullptr, qkvbuf, T_, 3*D_, D_, nullptr, nullptr);
        k_attn<<<dim3(NCHUNK_, NH_, B_), 256, 0, stream>>>(qkvbuf, abuf);
        k_mgemm<0,1,0,0,0><<<dim3(D_/128, 13), 256, 0, stream>>>(
            abuf, nullptr, wb_proj + (size_t)i*D_*D_, proj_b + (size_t)i*D_,
            z, z, T_, D_, D_, nullptr, nullptr);
        k_ln<bf16_t><<<T_, 256, 0, stream>>>(z, ln2_w + i*D_, ln2_b + i*D_, lnbuf, 1);
        if (i & 1){ // MoE layers 1,3,5,7,9,11
            hipMemsetAsync(counts, 0, 8*sizeof(int), stream);
            k_gate<<<dim3((T_+3)/4), 256, 0, stream>>>(
                lnbuf, gate_w + (size_t)mi*NE_*D_, gate_b + (size_t)mi*NE_,
                t_e, t_sc, counts);
            k_scan<<<1, 64, 0, stream>>>(counts, offs, cnt2);
            k_scatter<<<dim3((NSLOT_+255)/256), 256, 0, stream>>>(t_e, offs, cnt2, gidx, rg);
            k_mgemm<1,0,1,1,1><<<dim3(DH_/128, 25, NE_), 256, 0, stream>>>(
                lnbuf, gidx, wb_e1 + (size_t)mi*NE_*DH_*D_, exp_b1 + (size_t)mi*NE_*DH_,
                nullptr, hid, NSLOT_, DH_, D_, offs, counts);
            k_mgemm<0,0,0,1,0><<<dim3(D_/128, 25, NE_), 256, 0, stream>>>(
                hid, nullptr, wb_e2 + (size_t)mi*NE_*D_*DH_, exp_b2 + (size_t)mi*NE_*D_,
                nullptr, yb, NSLOT_, D_, DH_, offs, counts);
            k_combine<<<dim3((T_*D_+255)/256), 256, 0, stream>>>(yb, rg, t_sc, z);
            mi++;
        } else {
            k_mgemm<1,0,0,0,1><<<dim3(DH_/128, 13), 256, 0, stream>>>(
                lnbuf, nullptr, wb_fc1 + (size_t)di*DH_*D_, fc1_b + (size_t)di*DH_,
                nullptr, hid, T_, DH_, D_, nullptr, nullptr);
            k_mgemm<0,1,0,0,0><<<dim3(D_/128, 13), 256, 0, stream>>>(
                hid, nullptr, wb_fc2 + (size_t)di*D_*DH_, fc2_b + (size_t)di*D_,
                z, z, T_, D_, DH_, nullptr, nullptr);
            di++;
        }
    }
    // ---- final LN on cls tokens only + head ----
    k_ln<float><<<B_, 256, 0, stream>>>(z, norm_w, norm_b, zn, NTOK_);
    k_head<<<dim3((NCLS_+3)/4, B_), 256, 0, stream>>>(zn, head_w, head_b, (float*)d_out);
}

// Round 5
// 2987.124 us; speedup vs baseline: 7.4518x; 1.9435x over previous
//
#include <hip/hip_runtime.h>
#include <hip/hip_bf16.h>
#include <math.h>

#define B_     8
#define IMG_   224
#define PATCH_ 16
#define CIN_   3
#define D_     768
#define NH_    12
#define DEPTH_ 12
#define NE_    8
#define NCLS_  1000
#define DH_    3072
#define HD_    64
#define GRD_   14
#define NPAT_  196
#define NTOK_  197
#define T_     (B_*NTOK_)    /* 1576 tokens */
#define TP_    (B_*NPAT_)    /* 1568 patches */
#define NSLOT_ (T_*2)        /* 3152 (token,slot) pairs */

typedef __bf16 bf16_t;
typedef __bf16 bf16x8 __attribute__((ext_vector_type(8)));
typedef __bf16 bf16x4 __attribute__((ext_vector_type(4)));
typedef float  f32x4  __attribute__((ext_vector_type(4)));

static __device__ __forceinline__ float gelu_f(float x){
    return 0.5f * x * (1.0f + erff(x * 0.70710678118654752440f));
}

// ---------------- f32 -> bf16 bulk convert (8 elems/thread) ------------------
__global__ __launch_bounds__(256) void k_cvt(const float* __restrict__ in,
                                             bf16_t* __restrict__ out, int n){
    int i = (blockIdx.x*256 + threadIdx.x)*8;
    if (i >= n) return;
    float4 a = *reinterpret_cast<const float4*>(in + i);
    float4 b = *reinterpret_cast<const float4*>(in + i + 4);
    bf16x8 h;
    h[0]=(bf16_t)a.x; h[1]=(bf16_t)a.y; h[2]=(bf16_t)a.z; h[3]=(bf16_t)a.w;
    h[4]=(bf16_t)b.x; h[5]=(bf16_t)b.y; h[6]=(bf16_t)b.z; h[7]=(bf16_t)b.w;
    *reinterpret_cast<bf16x8*>(out + i) = h;
}

// ---------------- patch gather: x[B,3,224,224] -> pbuf[1568,768] bf16 -------
__global__ void k_patch_gather(const float* __restrict__ x, bf16_t* __restrict__ pbuf){
    int idx = blockIdx.x*256 + threadIdx.x;
    if (idx >= TP_*D_) return;
    int k  = idx % D_;
    int tp = idx / D_;
    int p  = tp % NPAT_, b = tp / NPAT_;
    int c  = k >> 8;
    int ij = k & 255;
    int i  = ij >> 4, j = ij & 15;
    int gi = p / GRD_, gj = p % GRD_;
    pbuf[idx] = (bf16_t)x[(((size_t)b*CIN_ + c)*IMG_ + gi*PATCH_ + i)*IMG_ + gj*PATCH_ + j];
}

// ---------------- bf16 MFMA GEMM v4 ------------------------------------------
// BM=64, BN=128, BK=64, 256 threads (4 waves x 32x64 output), dbuf 48KB LDS
// -> 3 blocks/CU. Both operands via global_load_lds dwordx4 (linear dest,
// pre-swizzled source chunk c^(row&7)); 2-phase prefetch.
template<int ACT, int RES, int GATHER, int MOE, int OUTBF>
__global__ __launch_bounds__(256) void k_mgemm(
    const bf16_t* __restrict__ A, const int* __restrict__ gidx,
    const bf16_t* __restrict__ W, const float* __restrict__ bias,
    const float* __restrict__ res, void* __restrict__ Cout,
    int M, int N, int K,
    const int* __restrict__ moff, const int* __restrict__ mcnt)
{
    __shared__ __align__(16) bf16_t As[2][64*64];
    __shared__ __align__(16) bf16_t Bs[2][128*64];
    const int tid = threadIdx.x, lane = tid & 63, w = tid >> 6;
    int row_begin, Mhi;
    if (MOE) {
        const int e = blockIdx.z;
        const int o = moff[e], c = mcnt[e];
        row_begin = o + blockIdx.y*64;
        Mhi = o + c;
        if (row_begin >= Mhi) return;
        W    += (size_t)e*N*K;
        bias += (size_t)e*N;
    } else {
        row_begin = blockIdx.y*64;
        Mhi = M;
    }
    const int bn = blockIdx.x*128;

    // staging: wave w owns A segments {2w,2w+1}, B segments {4w..4w+3} (8 rows each)
    const bf16_t* aG[2];
    const bf16_t* wG[4];
    int aOff[2], wOff[4];
    #pragma unroll
    for (int i = 0; i < 2; ++i) {
        const int s = w*2 + i;
        const int row_l = s*8 + (lane >> 3);
        const int cc = (lane & 7) ^ (row_l & 7);
        const int gg = min(row_begin + row_l, Mhi - 1);
        const int tok = GATHER ? (gidx[gg] >> 1) : gg;
        aG[i] = A + (size_t)tok*K + cc*8;
        aOff[i] = s*512;
    }
    #pragma unroll
    for (int j = 0; j < 4; ++j) {
        const int s = w*4 + j;
        const int row_l = s*8 + (lane >> 3);
        const int cc = (lane & 7) ^ (row_l & 7);
        wG[j] = W + (size_t)(bn + row_l)*K + cc*8;
        wOff[j] = s*512;
    }
    // frag read byte offsets
    const int wm = (w >> 1)*32, wn = (w & 1)*64;
    const int fr = lane & 15, kg = lane >> 4;
    int offA[2][2], offB[2][4];
    #pragma unroll
    for (int ks = 0; ks < 2; ++ks) {
        #pragma unroll
        for (int t = 0; t < 2; ++t) {
            const int ra = wm + t*16 + fr;
            offA[ks][t] = ra*128 + (((ks*4 + kg) ^ (ra & 7)) << 4);
        }
        #pragma unroll
        for (int t = 0; t < 4; ++t) {
            const int rb = wn + t*16 + fr;
            offB[ks][t] = rb*128 + (((ks*4 + kg) ^ (rb & 7)) << 4);
        }
    }

    f32x4 acc[2][4] = {};
    const int nt = K >> 6;
    int cur = 0;
    #pragma unroll
    for (int i = 0; i < 2; ++i) {
        __builtin_amdgcn_global_load_lds(
            (const __attribute__((address_space(1))) void*)(aG[i]),
            (__attribute__((address_space(3))) void*)(&As[0][aOff[i]]), 16, 0, 0);
        aG[i] += 64;
    }
    #pragma unroll
    for (int j = 0; j < 4; ++j) {
        __builtin_amdgcn_global_load_lds(
            (const __attribute__((address_space(1))) void*)(wG[j]),
            (__attribute__((address_space(3))) void*)(&Bs[0][wOff[j]]), 16, 0, 0);
        wG[j] += 64;
    }
    __syncthreads();
    for (int t = 0; t < nt; ++t) {
        if (t + 1 < nt) {
            const int nb = cur ^ 1;
            #pragma unroll
            for (int i = 0; i < 2; ++i) {
                __builtin_amdgcn_global_load_lds(
                    (const __attribute__((address_space(1))) void*)(aG[i]),
                    (__attribute__((address_space(3))) void*)(&As[nb][aOff[i]]), 16, 0, 0);
                aG[i] += 64;
            }
            #pragma unroll
            for (int j = 0; j < 4; ++j) {
                __builtin_amdgcn_global_load_lds(
                    (const __attribute__((address_space(1))) void*)(wG[j]),
                    (__attribute__((address_space(3))) void*)(&Bs[nb][wOff[j]]), 16, 0, 0);
                wG[j] += 64;
            }
        }
        const char* baseA = (const char*)&As[cur][0];
        const char* baseB = (const char*)&Bs[cur][0];
        #pragma unroll
        for (int ks = 0; ks < 2; ++ks) {
            bf16x8 af[2], bf[4];
            #pragma unroll
            for (int t2 = 0; t2 < 2; ++t2)
                af[t2] = *reinterpret_cast<const bf16x8*>(baseA + offA[ks][t2]);
            #pragma unroll
            for (int t2 = 0; t2 < 4; ++t2)
                bf[t2] = *reinterpret_cast<const bf16x8*>(baseB + offB[ks][t2]);
            #pragma unroll
            for (int mt = 0; mt < 2; ++mt)
                #pragma unroll
                for (int nt2 = 0; nt2 < 4; ++nt2)
                    acc[mt][nt2] = __builtin_amdgcn_mfma_f32_16x16x32_bf16(
                        af[mt], bf[nt2], acc[mt][nt2], 0, 0, 0);
        }
        __syncthreads();
        cur ^= 1;
    }
    float*  Cf = (float*)Cout;
    bf16_t* Cb = (bf16_t*)Cout;
    const int cr = (lane >> 4)*4;
    #pragma unroll
    for (int nt2 = 0; nt2 < 4; ++nt2) {
        const int n = bn + wn + nt2*16 + fr;
        const float bv = bias[n];
        #pragma unroll
        for (int mt = 0; mt < 2; ++mt) {
            #pragma unroll
            for (int r2 = 0; r2 < 4; ++r2) {
                const int m = row_begin + wm + mt*16 + cr + r2;
                if (m < Mhi) {
                    float v = acc[mt][nt2][r2] + bv;
                    if (ACT) v = gelu_f(v);
                    if (RES) v += res[(size_t)m*N + n];
                    if (OUTBF) Cb[(size_t)m*N + n] = (bf16_t)v;
                    else       Cf[(size_t)m*N + n] = v;
                }
            }
        }
    }
}

// ---------------- LN core (device) -------------------------------------------
// computes LN of 3 per-thread values; returns normalized*w+b
struct LNOut { float y0, y1, y2; };
static __device__ __forceinline__ LNOut ln_block(float v0, float v1, float v2,
        const float* __restrict__ w, const float* __restrict__ b,
        float* red, int tid)
{
    const int wid = tid >> 6, lane = tid & 63;
    float s = v0 + v1 + v2;
    for (int m=32;m>0;m>>=1) s += __shfl_xor(s, m);
    if (lane == 0) red[wid] = s;
    __syncthreads();
    if (tid == 0) red[4] = (red[0]+red[1]+red[2]+red[3]) * (1.0f/768.0f);
    __syncthreads();
    const float mean = red[4];
    float d0 = v0-mean, d1 = v1-mean, d2 = v2-mean;
    float q = d0*d0 + d1*d1 + d2*d2;
    for (int m=32;m>0;m>>=1) q += __shfl_xor(q, m);
    if (lane == 0) red[wid] = q;
    __syncthreads();
    if (tid == 0) {
        float var = (red[0]+red[1]+red[2]+red[3]) * (1.0f/768.0f);
        red[5] = 1.0f / sqrtf(var + 1e-5f);
    }
    __syncthreads();
    const float rstd = red[5];
    LNOut o;
    o.y0 = d0*rstd*w[tid    ] + b[tid    ];
    o.y1 = d1*rstd*w[tid+256] + b[tid+256];
    o.y2 = d2*rstd*w[tid+512] + b[tid+512];
    return o;
}

// ---------------- plain LayerNorm --------------------------------------------
template<typename TOUT>
__global__ __launch_bounds__(256) void k_ln(const float* __restrict__ X,
        const float* __restrict__ w, const float* __restrict__ b,
        TOUT* __restrict__ Y, int in_mul)
{
    __shared__ float red[8];
    const int r = blockIdx.x, tid = threadIdx.x;
    const float* xr = X + (size_t)r*in_mul*D_;
    LNOut o = ln_block(xr[tid], xr[tid+256], xr[tid+512], w, b, red, tid);
    TOUT* yr = Y + (size_t)r*D_;
    yr[tid] = (TOUT)o.y0; yr[tid+256] = (TOUT)o.y1; yr[tid+512] = (TOUT)o.y2;
}

// ---------------- assemble (cls/patch + pos) + LN1 of layer 0 ----------------
__global__ __launch_bounds__(256) void k_asmln(const float* __restrict__ pe,
        const float* __restrict__ cls, const float* __restrict__ pos,
        float* __restrict__ z, const float* __restrict__ w,
        const float* __restrict__ b, bf16_t* __restrict__ Y)
{
    __shared__ float red[8];
    const int t = blockIdx.x, tid = threadIdx.x;
    const int bb = t / NTOK_, r = t % NTOK_;
    float v[3];
    #pragma unroll
    for (int j = 0; j < 3; ++j) {
        const int n = tid + j*256;
        if (r == 0) v[j] = cls[n] + pos[n];
        else        v[j] = pe[((size_t)bb*NPAT_ + (r-1))*D_ + n] + pos[(size_t)r*D_ + n];
        z[(size_t)t*D_ + n] = v[j];
    }
    LNOut o = ln_block(v[0], v[1], v[2], w, b, red, tid);
    bf16_t* yr = Y + (size_t)t*D_;
    yr[tid] = (bf16_t)o.y0; yr[tid+256] = (bf16_t)o.y1; yr[tid+512] = (bf16_t)o.y2;
}

// ---------------- LN2 + MoE gate fused ---------------------------------------
__global__ __launch_bounds__(256) void k_lngate(const float* __restrict__ X,
        const float* __restrict__ w, const float* __restrict__ b,
        const float* __restrict__ gw, const float* __restrict__ gb,
        bf16_t* __restrict__ Y, int* __restrict__ t_e, float* __restrict__ t_sc)
{
    __shared__ float red[8];
    __shared__ float red2[4][8];
    const int t = blockIdx.x, tid = threadIdx.x;
    const int wid = tid >> 6, lane = tid & 63;
    const float* xr = X + (size_t)t*D_;
    LNOut o = ln_block(xr[tid], xr[tid+256], xr[tid+512], w, b, red, tid);
    bf16_t* yr = Y + (size_t)t*D_;
    yr[tid] = (bf16_t)o.y0; yr[tid+256] = (bf16_t)o.y1; yr[tid+512] = (bf16_t)o.y2;
    float p[NE_];
    #pragma unroll
    for (int e = 0; e < NE_; ++e)
        p[e] = o.y0*gw[e*D_+tid] + o.y1*gw[e*D_+tid+256] + o.y2*gw[e*D_+tid+512];
    #pragma unroll
    for (int e = 0; e < NE_; ++e)
        for (int m=32;m>0;m>>=1) p[e] += __shfl_xor(p[e], m);
    if (lane == 0)
        #pragma unroll
        for (int e = 0; e < NE_; ++e) red2[wid][e] = p[e];
    __syncthreads();
    if (tid == 0) {
        float l[NE_];
        #pragma unroll
        for (int e = 0; e < NE_; ++e)
            l[e] = red2[0][e]+red2[1][e]+red2[2][e]+red2[3][e] + gb[e];
        int i0 = 0;
        for (int e = 1; e < NE_; ++e) if (l[e] > l[i0]) i0 = e;
        int i1 = -1;
        for (int e = 0; e < NE_; ++e) if (e != i0 && (i1 < 0 || l[e] > l[i1])) i1 = e;
        float e1 = __expf(l[i1] - l[i0]);
        float s = 1.0f + e1;
        t_e[t*2]   = i0;   t_e[t*2+1]  = i1;
        t_sc[t*2]  = 1.0f/s; t_sc[t*2+1] = e1/s;
    }
}

// ---------------- scan+scatter: one block ------------------------------------
__global__ __launch_bounds__(256) void k_scansc(const int* __restrict__ t_e,
        int* __restrict__ gidx, int* __restrict__ rg,
        int* __restrict__ offs, int* __restrict__ counts)
{
    __shared__ int h[NE_], o[NE_], c2[NE_];
    const int tid = threadIdx.x;
    if (tid < NE_) h[tid] = 0;
    __syncthreads();
    for (int id = tid; id < NSLOT_; id += 256) atomicAdd(&h[t_e[id]], 1);
    __syncthreads();
    if (tid == 0) {
        int s = 0;
        for (int e = 0; e < NE_; ++e) { o[e] = s; s += h[e]; c2[e] = 0; }
    }
    __syncthreads();
    if (tid < NE_) { offs[tid] = o[tid]; counts[tid] = h[tid]; }
    for (int id = tid; id < NSLOT_; id += 256) {
        int e = t_e[id];
        int pos = atomicAdd(&c2[e], 1);
        int g = o[e] + pos;
        gidx[g] = id;
        rg[id] = g;
    }
}

// ---------------- combine + next-layer LN1 fused -----------------------------
__global__ __launch_bounds__(256) void k_combln(const float* __restrict__ yb,
        const int* __restrict__ rg, const float* __restrict__ t_sc,
        float* __restrict__ z, const float* __restrict__ w,
        const float* __restrict__ b, bf16_t* __restrict__ Y)
{
    __shared__ float red[8];
    const int t = blockIdx.x, tid = threadIdx.x;
    const int g0 = rg[t*2], g1 = rg[t*2+1];
    const float s0 = t_sc[t*2], s1 = t_sc[t*2+1];
    float v[3];
    #pragma unroll
    for (int j = 0; j < 3; ++j) {
        const int n = tid + j*256;
        float nv = z[(size_t)t*D_+n] + s0*yb[(size_t)g0*D_+n] + s1*yb[(size_t)g1*D_+n];
        z[(size_t)t*D_+n] = nv;
        v[j] = nv;
    }
    LNOut o = ln_block(v[0], v[1], v[2], w, b, red, tid);
    bf16_t* yr = Y + (size_t)t*D_;
    yr[tid] = (bf16_t)o.y0; yr[tid+256] = (bf16_t)o.y1; yr[tid+512] = (bf16_t)o.y2;
}

__global__ void k_combine(const float* __restrict__ yb, const int* __restrict__ rg,
                          const float* __restrict__ t_sc, float* __restrict__ z){
    int idx = blockIdx.x*256 + threadIdx.x;
    if (idx >= T_*D_) return;
    int t = idx / D_, n = idx % D_;
    int g0 = rg[t*2], g1 = rg[t*2+1];
    z[idx] += t_sc[t*2]*yb[(size_t)g0*D_+n] + t_sc[t*2+1]*yb[(size_t)g1*D_+n];
}

// ---------------- attention: wave-per-2-queries, barrier-free ----------------
// grid (25, NH, B), 256 threads (4 waves). K staged in LDS (stride 68, 2-way
// max bank), V read from global (L2-hot), ps in LDS as bf16.
__global__ __launch_bounds__(256) void k_attn(const bf16_t* __restrict__ qkv,
                                              bf16_t* __restrict__ out)
{
    __shared__ bf16_t Kl[NTOK_*68];
    __shared__ float  qs[8][64];
    __shared__ bf16_t ps[8][200];
    const int qb = blockIdx.x*8;
    const int h = blockIdx.y, b = blockIdx.z;
    const int tid = threadIdx.x, lane = tid & 63, wid = tid >> 6;
    // stage K (197 rows x 8 chunks of 8 bf16)
    for (int id = tid; id < NTOK_*8; id += 256) {
        const int m = id >> 3, c = id & 7;
        bf16x8 v = *reinterpret_cast<const bf16x8*>(
            qkv + (size_t)(b*NTOK_+m)*2304 + 768 + h*HD_ + c*8);
        bf16x4 lo = {v[0],v[1],v[2],v[3]}, hi = {v[4],v[5],v[6],v[7]};
        *reinterpret_cast<bf16x4*>(&Kl[m*68 + c*8    ]) = lo;
        *reinterpret_cast<bf16x4*>(&Kl[m*68 + c*8 + 4]) = hi;
    }
    // stage q (8 queries x 64 dims, f32)
    for (int id = tid; id < 512; id += 256) {
        const int qq = id >> 6, d = id & 63;
        const int n = qb + qq;
        qs[qq][d] = (n < NTOK_) ? (float)qkv[(size_t)(b*NTOK_+n)*2304 + h*HD_ + d] : 0.0f;
    }
    __syncthreads();
    const int na = qb + wid, nb = qb + wid + 4;
    const bool va = na < NTOK_, vb = nb < NTOK_;
    if (!va) return;           // (vb implies va)
    float sa[4] = {0,0,0,0}, sb[4] = {0,0,0,0};
    for (int d = 0; d < HD_; d += 4) {
        const f32x4 qa = *reinterpret_cast<const f32x4*>(&qs[wid][d]);
        const f32x4 qv = *reinterpret_cast<const f32x4*>(&qs[wid+4][d]);
        #pragma unroll
        for (int j = 0; j < 4; ++j) {
            const int m = lane + 64*j;
            const int mc = m < NTOK_ ? m : NTOK_-1;
            bf16x4 kv = *reinterpret_cast<const bf16x4*>(&Kl[mc*68 + d]);
            float k0=(float)kv[0], k1=(float)kv[1], k2=(float)kv[2], k3=(float)kv[3];
            sa[j] += qa[0]*k0 + qa[1]*k1 + qa[2]*k2 + qa[3]*k3;
            sb[j] += qv[0]*k0 + qv[1]*k1 + qv[2]*k2 + qv[3]*k3;
        }
    }
    #pragma unroll
    for (int j = 0; j < 4; ++j) {
        const bool ok = (lane + 64*j) < NTOK_;
        sa[j] = ok ? sa[j]*0.125f : -3.0e38f;
        sb[j] = ok ? sb[j]*0.125f : -3.0e38f;
    }
    // softmax (per-wave, shuffle only)
    float mxa = fmaxf(fmaxf(sa[0],sa[1]), fmaxf(sa[2],sa[3]));
    float mxb = fmaxf(fmaxf(sb[0],sb[1]), fmaxf(sb[2],sb[3]));
    for (int m=32;m>0;m>>=1) { mxa = fmaxf(mxa, __shfl_xor(mxa,m)); mxb = fmaxf(mxb, __shfl_xor(mxb,m)); }
    float pa[4], pb[4], suma = 0.0f, sumb = 0.0f;
    #pragma unroll
    for (int j = 0; j < 4; ++j) {
        pa[j] = __expf(sa[j]-mxa); suma += pa[j];
        pb[j] = __expf(sb[j]-mxb); sumb += pb[j];
    }
    for (int m=32;m>0;m>>=1) { suma += __shfl_xor(suma,m); sumb += __shfl_xor(sumb,m); }
    #pragma unroll
    for (int j = 0; j < 4; ++j) {
        const int m = lane + 64*j;
        if (m < NTOK_) {
            ps[wid][m] = (bf16_t)pa[j];
            if (vb) ps[wid+4][m] = (bf16_t)pb[j];
        }
    }
    const float inva = 1.0f/suma, invb = 1.0f/sumb;
    // PV: d = lane, V from global (coalesced 128B rows, L2-hot)
    const bf16_t* vbase = qkv + (size_t)b*NTOK_*2304 + 1536 + h*HD_ + lane;
    float aa = 0.0f, ab = 0.0f;
    if (vb) {
        for (int m = 0; m < NTOK_; ++m) {
            const float vv = (float)vbase[(size_t)m*2304];
            aa += (float)ps[wid][m]*vv;
            ab += (float)ps[wid+4][m]*vv;
        }
    } else {
        for (int m = 0; m < NTOK_; ++m)
            aa += (float)ps[wid][m]*(float)vbase[(size_t)m*2304];
    }
    out[(size_t)(b*NTOK_+na)*D_ + h*HD_ + lane] = (bf16_t)(aa*inva);
    if (vb) out[(size_t)(b*NTOK_+nb)*D_ + h*HD_ + lane] = (bf16_t)(ab*invb);
}

// ---------------- head: wave per class ---------------------------------------
__global__ __launch_bounds__(256) void k_head(const float* __restrict__ zn,
        const float* __restrict__ hw, const float* __restrict__ hb,
        float* __restrict__ out)
{
    const int o = blockIdx.x*4 + (threadIdx.x >> 6);
    const int b = blockIdx.y;
    const int lane = threadIdx.x & 63;
    if (o >= NCLS_) return;
    float acc = 0.0f;
    #pragma unroll 4
    for (int k = lane; k < D_; k += 64)
        acc = fmaf(zn[b*D_+k], hw[(size_t)o*D_+k], acc);
    for (int m=32;m>0;m>>=1) acc += __shfl_xor(acc, m);
    if (lane == 0) out[b*NCLS_+o] = acc + hb[o];
}

// =============================================================================
extern "C" void kernel_launch(void* const* d_in, const int* in_sizes, int n_in,
                              void* d_out, int out_size, void* d_ws, size_t ws_size,
                              hipStream_t stream)
{
    const float* x        = (const float*)d_in[0];
    const float* patch_w  = (const float*)d_in[1];
    const float* patch_b  = (const float*)d_in[2];
    const float* cls_tok  = (const float*)d_in[3];
    const float* pos_emb  = (const float*)d_in[4];
    const float* ln1_w    = (const float*)d_in[5];
    const float* ln1_b    = (const float*)d_in[6];
    const float* qkv_w    = (const float*)d_in[7];
    const float* qkv_b    = (const float*)d_in[8];
    const float* proj_w   = (const float*)d_in[9];
    const float* proj_b   = (const float*)d_in[10];
    const float* ln2_w    = (const float*)d_in[11];
    const float* ln2_b    = (const float*)d_in[12];
    const float* fc1_w    = (const float*)d_in[13];
    const float* fc1_b    = (const float*)d_in[14];
    const float* fc2_w    = (const float*)d_in[15];
    const float* fc2_b    = (const float*)d_in[16];
    const float* gate_w   = (const float*)d_in[17];
    const float* gate_b   = (const float*)d_in[18];
    const float* exp_w1   = (const float*)d_in[19];
    const float* exp_b1   = (const float*)d_in[20];
    const float* exp_w2   = (const float*)d_in[21];
    const float* exp_b2   = (const float*)d_in[22];
    const float* norm_w   = (const float*)d_in[23];
    const float* norm_b   = (const float*)d_in[24];
    const float* head_w   = (const float*)d_in[25];
    const float* head_b   = (const float*)d_in[26];

    char* wsb = (char*)d_ws;
    size_t off_ = 0;
    auto alloc = [&](size_t nelem, size_t esz) -> void* {
        void* p = wsb + off_;
        off_ += ((nelem*esz + 255) / 256) * 256;
        return p;
    };
    float*  z      = (float*) alloc((size_t)T_*D_, 4);
    bf16_t* lnbuf  = (bf16_t*)alloc((size_t)T_*D_, 2);
    bf16_t* qkvbuf = (bf16_t*)alloc((size_t)T_*3*D_, 2);
    bf16_t* abuf   = (bf16_t*)alloc((size_t)T_*D_, 2);
    bf16_t* hid    = (bf16_t*)alloc((size_t)NSLOT_*DH_, 2);
    float*  yb     = (float*) alloc((size_t)NSLOT_*D_, 4);
    float*  t_sc   = (float*) alloc(NSLOT_, 4);
    float*  zn     = (float*) alloc((size_t)B_*D_, 4);
    int*    t_e    = (int*)   alloc(NSLOT_, 4);
    int*    rg     = (int*)   alloc(NSLOT_, 4);
    int*    gidx   = (int*)   alloc(NSLOT_, 4);
    int*    offs   = (int*)   alloc(8, 4);
    int*    counts = (int*)   alloc(8, 4);
    const size_t n_patch = (size_t)D_*D_;
    const size_t n_qkv   = (size_t)DEPTH_*3*D_*D_;
    const size_t n_proj  = (size_t)DEPTH_*D_*D_;
    const size_t n_fc1   = (size_t)6*DH_*D_;
    const size_t n_fc2   = (size_t)6*D_*DH_;
    const size_t n_e1    = (size_t)6*NE_*DH_*D_;
    const size_t n_e2    = (size_t)6*NE_*D_*DH_;
    bf16_t* wb_patch = (bf16_t*)alloc(n_patch, 2);
    bf16_t* wb_qkv   = (bf16_t*)alloc(n_qkv, 2);
    bf16_t* wb_proj  = (bf16_t*)alloc(n_proj, 2);
    bf16_t* wb_fc1   = (bf16_t*)alloc(n_fc1, 2);
    bf16_t* wb_fc2   = (bf16_t*)alloc(n_fc2, 2);
    bf16_t* wb_e1    = (bf16_t*)alloc(n_e1, 2);
    bf16_t* wb_e2    = (bf16_t*)alloc(n_e2, 2);
    bf16_t* pbuf   = hid;      // patch staging, dead before fc1 first writes hid
    float*  pout   = yb;       // patch-proj f32 out, dead before MoE writes yb

    // ---- weight pre-convert (f32 -> bf16) ----
    auto cvt = [&](const float* src, bf16_t* dst, size_t n){
        k_cvt<<<dim3((unsigned)((n/8 + 255)/256)), 256, 0, stream>>>(src, dst, (int)n);
    };
    cvt(patch_w, wb_patch, n_patch);
    cvt(qkv_w,   wb_qkv,   n_qkv);
    cvt(proj_w,  wb_proj,  n_proj);
    cvt(fc1_w,   wb_fc1,   n_fc1);
    cvt(fc2_w,   wb_fc2,   n_fc2);
    cvt(exp_w1,  wb_e1,    n_e1);
    cvt(exp_w2,  wb_e2,    n_e2);

    // ---- patch embedding + assemble + LN1(layer 0) ----
    k_patch_gather<<<dim3((TP_*D_+255)/256), 256, 0, stream>>>(x, pbuf);
    k_mgemm<0,0,0,0,0><<<dim3(D_/128, (TP_+63)/64), 256, 0, stream>>>(
        pbuf, nullptr, wb_patch, patch_b, nullptr, pout, TP_, D_, D_, nullptr, nullptr);
    k_asmln<<<T_, 256, 0, stream>>>(pout, cls_tok, pos_emb, z, ln1_w, ln1_b, lnbuf);

    const int GY = (T_+63)/64;   // 25
    int di = 0, mi = 0;
    for (int i = 0; i < DEPTH_; ++i){
        // lnbuf holds LN1(z) on entry
        k_mgemm<0,0,0,0,1><<<dim3(3*D_/128, GY), 256, 0, stream>>>(
            lnbuf, nullptr, wb_qkv + (size_t)i*3*D_*D_, qkv_b + (size_t)i*3*D_,
            nullptr, qkvbuf, T_, 3*D_, D_, nullptr, nullptr);
        k_attn<<<dim3((NTOK_+7)/8, NH_, B_), 256, 0, stream>>>(qkvbuf, abuf);
        k_mgemm<0,1,0,0,0><<<dim3(D_/128, GY), 256, 0, stream>>>(
            abuf, nullptr, wb_proj + (size_t)i*D_*D_, proj_b + (size_t)i*D_,
            z, z, T_, D_, D_, nullptr, nullptr);
        if (i & 1){ // MoE layers 1,3,5,7,9,11
            k_lngate<<<T_, 256, 0, stream>>>(z, ln2_w + i*D_, ln2_b + i*D_,
                gate_w + (size_t)mi*NE_*D_, gate_b + (size_t)mi*NE_,
                lnbuf, t_e, t_sc);
            k_scansc<<<1, 256, 0, stream>>>(t_e, gidx, rg, offs, counts);
            k_mgemm<1,0,1,1,1><<<dim3(DH_/128, 50, NE_), 256, 0, stream>>>(
                lnbuf, gidx, wb_e1 + (size_t)mi*NE_*DH_*D_, exp_b1 + (size_t)mi*NE_*DH_,
                nullptr, hid, NSLOT_, DH_, D_, offs, counts);
            k_mgemm<0,0,0,1,0><<<dim3(D_/128, 50, NE_), 256, 0, stream>>>(
                hid, nullptr, wb_e2 + (size_t)mi*NE_*D_*DH_, exp_b2 + (size_t)mi*NE_*D_,
                nullptr, yb, NSLOT_, D_, DH_, offs, counts);
            if (i + 1 < DEPTH_) {
                k_combln<<<T_, 256, 0, stream>>>(yb, rg, t_sc, z,
                    ln1_w + (i+1)*D_, ln1_b + (i+1)*D_, lnbuf);
            } else {
                k_combine<<<dim3((T_*D_+255)/256), 256, 0, stream>>>(yb, rg, t_sc, z);
            }
            mi++;
        } else {
            k_ln<bf16_t><<<T_, 256, 0, stream>>>(z, ln2_w + i*D_, ln2_b + i*D_, lnbuf, 1);
            k_mgemm<1,0,0,0,1><<<dim3(DH_/128, GY), 256, 0, stream>>>(
                lnbuf, nullptr, wb_fc1 + (size_t)di*DH_*D_, fc1_b + (size_t)di*DH_,
                nullptr, hid, T_, DH_, D_, nullptr, nullptr);
            k_mgemm<0,1,0,0,0><<<dim3(D_/128, GY), 256, 0, stream>>>(
                hid, nullptr, wb_fc2 + (size_t)di*D_*DH_, fc2_b + (size_t)di*D_,
                z, z, T_, D_, DH_, nullptr, nullptr);
            k_ln<bf16_t><<<T_, 256, 0, stream>>>(z, ln1_w + (i+1)*D_, ln1_b + (i+1)*D_, lnbuf, 1);
            di++;
        }
    }
    // ---- final LN on cls tokens only + head ----
    k_ln<float><<<B_, 256, 0, stream>>>(z, norm_w, norm_b, zn, NTOK_);
    k_head<<<dim3((NCLS_+3)/4, B_), 256, 0, stream>>>(zn, head_w, head_b, (float*)d_out);
}